// Round 11
// baseline (453.360 us; speedup 1.0000x reference)
//
#include <hip/hip_runtime.h>
#include <hip/hip_bf16.h>
#include <math.h>

#define BB 64
#define NN 16
#define HH 100
#define DD 400
#define AA 200
#define CATN 19
#define NODES 118            // HH + CATN-1
#define BN (BB*NODES)        // 7552
#define BH (BB*HH)           // 6400
#define ATT_INV 0.07071067811865475f   // 1/sqrt(200)

typedef __attribute__((ext_vector_type(4))) float f32x4;
typedef __attribute__((ext_vector_type(8))) short s16x8;

__device__ __forceinline__ unsigned short f2bf(float f) {
  union { float f; unsigned int u; } v; v.f = f;
  unsigned int r = v.u + 0x7FFFu + ((v.u >> 16) & 1u);
  return (unsigned short)(r >> 16);
}
__device__ __forceinline__ float bf2f(unsigned short u) {
  union { unsigned int i; float f; } v; v.i = ((unsigned int)u) << 16; return v.f;
}

// ---------------- fused concat + transpose: he fp32 + hT bf16 [b][416][128]
__global__ __launch_bounds__(256) void k_toT_he(const float* __restrict__ hist,
    const float* __restrict__ proxy, float* __restrict__ he,
    unsigned short* __restrict__ T) {
  __shared__ float t_sh[64][129];
  const int b = blockIdx.x / 7, dt = blockIdx.x % 7;
  const int d0 = dt * 64;
  const int tid = threadIdx.x;
  const int dc = tid & 63, jr = tid >> 6;
  for (int j0 = 0; j0 < 128; j0 += 4) {
    int j = j0 + jr, d = d0 + dc;
    float v = 0.f;
    if (j < NODES && d < DD) {
      v = (j < HH) ? hist[((size_t)b * HH + j) * DD + d]
                   : proxy[(size_t)(j - HH) * DD + d];
      he[((size_t)b * NODES + j) * DD + d] = v;
    }
    t_sh[dc][j] = v;
  }
  __syncthreads();
  const int jc = tid & 127, dr2 = tid >> 7;
  for (int di = 0; di < 64; di += 2) {
    int dr = di + dr2;
    int d = d0 + dr;
    if (d < 416) T[((size_t)b * 416 + d) * 128 + jc] = f2bf(t_sh[dr][jc]);
  }
}

// ---------------- transpose h[b][RPB][400] fp32 -> T[b][416][128] bf16
template<int RPB>
__global__ __launch_bounds__(256) void k_toT(const float* __restrict__ h,
    unsigned short* __restrict__ T) {
  __shared__ float t_sh[64][129];
  const int b = blockIdx.x / 7, dt = blockIdx.x % 7;
  const int d0 = dt * 64;
  const int tid = threadIdx.x;
  const int dc = tid & 63, jr = tid >> 6;
  for (int j0 = 0; j0 < 128; j0 += 4) {
    int j = j0 + jr, d = d0 + dc;
    float v = (j < RPB && d < DD) ? h[((size_t)b * RPB + j) * DD + d] : 0.f;
    t_sh[dc][j] = v;
  }
  __syncthreads();
  const int jc = tid & 127, dr2 = tid >> 7;
  for (int di = 0; di < 64; di += 2) {
    int dr = di + dr2;
    int d = d0 + dr;
    if (d < 416) T[((size_t)b * 416 + d) * 128 + jc] = f2bf(t_sh[dr][jc]);
  }
}

// ---------------- fused gf = (h2+he)[:, :HH] + transpose -> gf fp32 + gfT bf16
__global__ __launch_bounds__(256) void k_toT_gf(const float* __restrict__ h2,
    const float* __restrict__ he, float* __restrict__ gf,
    unsigned short* __restrict__ T) {
  __shared__ float t_sh[64][129];
  const int b = blockIdx.x / 7, dt = blockIdx.x % 7;
  const int d0 = dt * 64;
  const int tid = threadIdx.x;
  const int dc = tid & 63, jr = tid >> 6;
  for (int j0 = 0; j0 < 128; j0 += 4) {
    int j = j0 + jr, d = d0 + dc;
    float v = 0.f;
    if (j < HH && d < DD) {
      size_t src = ((size_t)b * NODES + j) * DD + d;
      v = h2[src] + he[src];
      gf[((size_t)b * HH + j) * DD + d] = v;
    }
    t_sh[dc][j] = v;
  }
  __syncthreads();
  const int jc = tid & 127, dr2 = tid >> 7;
  for (int di = 0; di < 64; di += 2) {
    int dr = di + dr2;
    int d = d0 + dr;
    if (d < 416) T[((size_t)b * 416 + d) * 128 + jc] = f2bf(t_sh[dr][jc]);
  }
}

// ---------------- fused GCN layer: GEMM1 (G@h via hT) -> LDS -> GEMM2 (@gW)
// -> LN(relu(x+b)+resid). Grid 256 = 64b x 4 row-quarters, b-chunked XCD.
__global__ __launch_bounds__(256) void k_gln(const float* __restrict__ G,
    const unsigned short* __restrict__ hT, const float* __restrict__ resid,
    const unsigned short* __restrict__ Wt, const float* __restrict__ bias,
    const float* __restrict__ lns, const float* __restrict__ lnb,
    float* __restrict__ out) {
  __shared__ unsigned short g_sh[32 * 136];
  __shared__ unsigned short o_sh[32 * 424];
  __shared__ float ps_sh[32][2][2];
  const int tid = threadIdx.x;
  const int g = (blockIdx.x & 7) * (gridDim.x >> 3) + (blockIdx.x >> 3);
  const int b = g >> 2;
  const int i0 = (g & 3) * 32;
  // stage G rows i0..i0+31 (bf16, zero-pad)
  for (int idx = tid; idx < 32 * 128; idx += 256) {
    int r = idx >> 7, j = idx & 127;
    int i = i0 + r;
    float v = (i < NODES && j < NODES) ? G[((size_t)b * NODES + i) * NODES + j] : 0.f;
    g_sh[r * 136 + j] = f2bf(v);
  }
  __syncthreads();
  const int lane = tid & 63, w = tid >> 6;
  const int lrow = lane & 15, lk = lane >> 4;
  const int rg = w & 1, nh = w >> 1;
  const int cbeg = nh * 13;
  const int r0 = rg * 16 + lk * 4;
  // --- GEMM1: tmp = G @ h ---
  {
    f32x4 acc[13];
#pragma unroll
    for (int c = 0; c < 13; ++c) acc[c] = f32x4{0.f, 0.f, 0.f, 0.f};
    const unsigned short* ap = &g_sh[(rg * 16 + lrow) * 136 + lk * 8];
    const unsigned short* wp = &hT[((size_t)b * 416 + cbeg * 16 + lrow) * 128 + lk * 8];
    for (int ks = 0; ks < 4; ++ks) {
      s16x8 af = *reinterpret_cast<const s16x8*>(ap + ks * 32);
#pragma unroll
      for (int c = 0; c < 13; ++c) {
        s16x8 bf = *reinterpret_cast<const s16x8*>(wp + (size_t)c * 16 * 128 + ks * 32);
        acc[c] = __builtin_amdgcn_mfma_f32_16x16x32_bf16(af, bf, acc[c], 0, 0, 0);
      }
    }
#pragma unroll
    for (int c = 0; c < 13; ++c) {
      int col = (cbeg + c) * 16 + lrow;
#pragma unroll
      for (int j = 0; j < 4; ++j)
        o_sh[(r0 + j) * 424 + col] = f2bf(acc[c][j]);
    }
  }
  __syncthreads();
  // --- GEMM2: o_sh @ Wt ---
  f32x4 acc2[13];
#pragma unroll
  for (int c = 0; c < 13; ++c) acc2[c] = f32x4{0.f, 0.f, 0.f, 0.f};
  {
    const unsigned short* ap = &o_sh[(rg * 16 + lrow) * 424 + lk * 8];
    const unsigned short* wp = &Wt[((size_t)(cbeg * 16) + lrow) * 416 + lk * 8];
    for (int ks = 0; ks < 13; ++ks) {
      s16x8 af = *reinterpret_cast<const s16x8*>(ap + ks * 32);
#pragma unroll
      for (int c = 0; c < 13; ++c) {
        s16x8 bf = *reinterpret_cast<const s16x8*>(wp + (size_t)c * 16 * 416 + ks * 32);
        acc2[c] = __builtin_amdgcn_mfma_f32_16x16x32_bf16(af, bf, acc2[c], 0, 0, 0);
      }
    }
  }
  // --- LN epilogue ---
  float zs[4], zq[4];
#pragma unroll
  for (int j = 0; j < 4; ++j) { zs[j] = 0.f; zq[j] = 0.f; }
#pragma unroll
  for (int c = 0; c < 13; ++c) {
    int col = (cbeg + c) * 16 + lrow;
    bool cv = col < DD;
    float bv = cv ? bias[col] : 0.f;
#pragma unroll
    for (int j = 0; j < 4; ++j) {
      int i = i0 + r0 + j;
      float z = 0.f;
      if (cv && i < NODES)
        z = fmaxf(acc2[c][j] + bv, 0.f) + resid[((size_t)b * NODES + i) * DD + col];
      acc2[c][j] = z;
      zs[j] += z;
      zq[j] += z * z;
    }
  }
#pragma unroll
  for (int j = 0; j < 4; ++j) {
    zs[j] += __shfl_xor(zs[j], 1, 64); zq[j] += __shfl_xor(zq[j], 1, 64);
    zs[j] += __shfl_xor(zs[j], 2, 64); zq[j] += __shfl_xor(zq[j], 2, 64);
    zs[j] += __shfl_xor(zs[j], 4, 64); zq[j] += __shfl_xor(zq[j], 4, 64);
    zs[j] += __shfl_xor(zs[j], 8, 64); zq[j] += __shfl_xor(zq[j], 8, 64);
  }
  if (lrow == 0) {
#pragma unroll
    for (int j = 0; j < 4; ++j) {
      ps_sh[r0 + j][nh][0] = zs[j];
      ps_sh[r0 + j][nh][1] = zq[j];
    }
  }
  __syncthreads();
  float mu[4], rs[4];
#pragma unroll
  for (int j = 0; j < 4; ++j) {
    float s = ps_sh[r0 + j][0][0] + ps_sh[r0 + j][1][0];
    float q2 = ps_sh[r0 + j][0][1] + ps_sh[r0 + j][1][1];
    mu[j] = s * (1.0f / DD);
    float var = q2 * (1.0f / DD) - mu[j] * mu[j];
    rs[j] = 1.0f / sqrtf(var + 1e-5f);
  }
#pragma unroll
  for (int c = 0; c < 13; ++c) {
    int col = (cbeg + c) * 16 + lrow;
    if (col < DD) {
      float sc = lns[col], bo = lnb[col];
#pragma unroll
      for (int j = 0; j < 4; ++j) {
        int i = i0 + r0 + j;
        if (i < NODES)
          out[((size_t)b * NODES + i) * DD + col] = (acc2[c][j] - mu[j]) * rs[j] * sc + bo;
      }
    }
  }
}

// ---------------- one-shot weight prep (bf16 transposed+padded blobs)
__global__ __launch_bounds__(256) void k_prep_all(const float* __restrict__ gW,
    const float* __restrict__ afW, const float* __restrict__ Kw,
    const float* __restrict__ Qw, const float* __restrict__ icQw,
    const float* __restrict__ icKw, const float* __restrict__ Qb,
    const float* __restrict__ icQb, unsigned short* __restrict__ wbase,
    float* __restrict__ bias3) {
  int idx = blockIdx.x * 256 + threadIdx.x;
  const int SG = 416 * 416;   // 173056
  const int SK = 224 * 416;   // 93184
  if (idx < SG) {             // gW0t
    int n = idx / 416, k = idx - n * 416;
    wbase[idx] = (n < 400 && k < 400) ? f2bf(gW[(size_t)k * 400 + n]) : (unsigned short)0;
    return;
  }
  idx -= SG;
  if (idx < SG) {             // gW1t
    int n = idx / 416, k = idx - n * 416;
    wbase[173056 + idx] = (n < 400 && k < 400) ? f2bf(gW[160000 + (size_t)k * 400 + n]) : (unsigned short)0;
    return;
  }
  idx -= SG;
  if (idx < SG) {             // afWt
    int n = idx / 416, k = idx - n * 416;
    wbase[346112 + idx] = (n < 400 && k < 400) ? f2bf(afW[(size_t)k * 400 + n]) : (unsigned short)0;
    return;
  }
  idx -= SG;
  if (idx < SK) {             // Kwt [224 n][416 k]
    int n = idx / 416, k = idx - n * 416;
    wbase[519168 + idx] = (n < 200 && k < 400) ? f2bf(Kw[(size_t)k * 200 + n]) : (unsigned short)0;
    return;
  }
  idx -= SK;
  if (idx < SK) {             // icKwB [416 d][224 a]
    int d = idx / 224, a = idx - d * 224;
    wbase[612352 + idx] = (d < 400 && a < 200) ? f2bf(icKw[(size_t)d * 200 + a]) : (unsigned short)0;
    return;
  }
  idx -= SK;
  if (idx < SK) {             // icQwB [416 k][224 a]
    int k = idx / 224, a = idx - k * 224;
    wbase[705536 + idx] = (k < 400 && a < 200) ? f2bf(icQw[(size_t)k * 200 + a]) : (unsigned short)0;
    return;
  }
  idx -= SK;
  if (idx < 208 * 416) {      // Wqp rows 0..207 (Q part)
    int n = idx / 416, k = idx - n * 416;
    wbase[798720 + idx] = (n < 200 && k < 400) ? f2bf(Qw[(size_t)k * 200 + n]) : (unsigned short)0;
    return;
  }
  idx -= 208 * 416;
  if (idx < 608) {            // bias3
    float v = 0.f;
    if (idx < 200) v = Qb[idx];
    else if (idx >= 208) {
      const float* kr = icKw + (size_t)(idx - 208) * 200;
      float s = 0.f;
      for (int a = 0; a < 200; ++a) s += icQb[a] * kr[a];
      v = s;
    }
    bias3[idx] = v;
  }
}

// ---------------- M-prep: Wqp[208+d][k] = bf16( sum_a icKw[d,a]*icQw[k,a] ), MFMA
__global__ __launch_bounds__(256) void k_prep_M(const unsigned short* __restrict__ icKwB,
    const unsigned short* __restrict__ icQwB, unsigned short* __restrict__ wqp) {
  const int tid = threadIdx.x;
  const size_t row0 = (size_t)blockIdx.x * 32;
  const int lane = tid & 63, w = tid >> 6;
  const int lrow = lane & 15, lk = lane >> 4;
  const int rg = w & 1, nh = w >> 1;
  const int cbeg = nh * 13;
  f32x4 acc[13];
#pragma unroll
  for (int c = 0; c < 13; ++c) acc[c] = f32x4{0.f, 0.f, 0.f, 0.f};
  const unsigned short* ap = &icKwB[(row0 + rg * 16 + lrow) * 224 + lk * 8];
  const unsigned short* bp = &icQwB[((size_t)(cbeg * 16) + lrow) * 224 + lk * 8];
  for (int ks = 0; ks < 7; ++ks) {
    s16x8 af = *reinterpret_cast<const s16x8*>(ap + ks * 32);
#pragma unroll
    for (int c = 0; c < 13; ++c) {
      s16x8 bf = *reinterpret_cast<const s16x8*>(bp + (size_t)c * 16 * 224 + ks * 32);
      acc[c] = __builtin_amdgcn_mfma_f32_16x16x32_bf16(af, bf, acc[c], 0, 0, 0);
    }
  }
  const int r0 = rg * 16 + lk * 4;
#pragma unroll
  for (int c = 0; c < 13; ++c) {
    int k = (cbeg + c) * 16 + lrow;
#pragma unroll
    for (int j = 0; j < 4; ++j) {
      size_t d = row0 + r0 + j;
      if (d < 400) wqp[(208 + d) * 416 + k] = f2bf(acc[c][j]);
    }
  }
}

// =================== fp32-A MFMA GEMM (v1 decomposition, XCD row-chunk swizzle)
// EPI: 0 plain(colguard), 6 QP dual-output.
template<int KDIM, int KPAD, int NOUT, int EPI>
__global__ __launch_bounds__(256) void k_mg(
    const float* __restrict__ A, const unsigned short* __restrict__ Wt,
    const float* __restrict__ bias, float* __restrict__ out, float* __restrict__ out2) {
  constexpr int APITCH = KPAD + 8;
  constexpr int NF = (NOUT + 15) / 16;
  constexpr int NF0 = (NF + 1) / 2;
  constexpr int KS = KPAD / 32;
  constexpr int E4 = KDIM / 4;
  constexpr int PADN = KPAD - KDIM;
  __shared__ unsigned short a_sh[32 * APITCH];
  const int tid = threadIdx.x;
  const int g = (blockIdx.x % 8) * (gridDim.x / 8) + blockIdx.x / 8;
  const size_t row0 = (size_t)g * 32;
  for (int i = tid; i < 32 * E4; i += 256) {
    int r = i / E4, c4 = i - r * E4;
    const float4 v = *reinterpret_cast<const float4*>(&A[(row0 + r) * (size_t)KDIM + c4 * 4]);
    unsigned int lo = (unsigned int)f2bf(v.x) | ((unsigned int)f2bf(v.y) << 16);
    unsigned int hi = (unsigned int)f2bf(v.z) | ((unsigned int)f2bf(v.w) << 16);
    *reinterpret_cast<uint2*>(&a_sh[r * APITCH + c4 * 4]) = make_uint2(lo, hi);
  }
  for (int i = tid; i < 32 * PADN; i += 256) {
    int r = i / PADN, c = i - r * PADN;
    a_sh[r * APITCH + KDIM + c] = 0;
  }
  __syncthreads();
  const int lane = tid & 63, w = tid >> 6;
  const int lrow = lane & 15, lk = lane >> 4;
  const int rg = w & 1, nh = w >> 1;
  const int cbeg = nh * NF0;
  f32x4 acc[NF0];
#pragma unroll
  for (int c = 0; c < NF0; ++c) acc[c] = f32x4{0.f, 0.f, 0.f, 0.f};
  const unsigned short* ap = &a_sh[(rg * 16 + lrow) * APITCH + lk * 8];
  const unsigned short* wp = &Wt[((size_t)(cbeg * 16) + lrow) * KPAD + lk * 8];
  for (int ks = 0; ks < KS; ++ks) {
    s16x8 af = *reinterpret_cast<const s16x8*>(ap + ks * 32);
#pragma unroll
    for (int c = 0; c < NF0; ++c) {
      s16x8 bf = *reinterpret_cast<const s16x8*>(wp + (size_t)c * 16 * KPAD + ks * 32);
      acc[c] = __builtin_amdgcn_mfma_f32_16x16x32_bf16(af, bf, acc[c], 0, 0, 0);
    }
  }
  const int r0 = rg * 16 + lk * 4;
  if (EPI == 0) {
#pragma unroll
    for (int c = 0; c < NF0; ++c) {
      int col = (cbeg + c) * 16 + lrow;
      if (col < NOUT) {
#pragma unroll
        for (int j = 0; j < 4; ++j)
          out[(row0 + r0 + j) * (size_t)NOUT + col] = acc[c][j];
      }
    }
  } else {  // EPI == 6
#pragma unroll
    for (int c = 0; c < NF0; ++c) {
      int col = (cbeg + c) * 16 + lrow;
      if (col < 200) {
        float bv = bias[col];
#pragma unroll
        for (int j = 0; j < 4; ++j)
          out[(row0 + r0 + j) * (size_t)AA + col] = acc[c][j] + bv;
      } else if (col >= 208 && col < 608) {
        float bv = bias[col];
#pragma unroll
        for (int j = 0; j < 4; ++j)
          out2[(row0 + r0 + j) * (size_t)DD + (col - 208)] = acc[c][j] + bv;
      }
    }
  }
}

// --------- alpha segment-softmax -> P bf16 [b][320 pitch][128]  (b-chunked XCD)
__global__ __launch_bounds__(256) void k_palpha(const float* __restrict__ K,
    const float* __restrict__ Q, const int* __restrict__ cat,
    unsigned short* __restrict__ P) {
  __shared__ float q_sh[AA];
  __shared__ float a_sh[HH];
  __shared__ int c_sh[HH];
  __shared__ float smax[CATN], sden[CATN];
  const int i = blockIdx.x;
  const int xcd = i & 7, s = i >> 3;
  const int b = 8 * xcd + (s >> 4);
  const int n = s & 15;
  const int bn = b * 16 + n;
  const int tid = threadIdx.x;
  if (tid < AA) q_sh[tid] = Q[(size_t)bn * AA + tid];
  if (tid < HH) c_sh[tid] = cat[b * HH + tid];
  __syncthreads();
  if (tid < 2 * HH) {
    int h = tid >> 1, half = tid & 1;
    const float* kp = K + ((size_t)b * HH + h) * AA + half * 100;
    const float* qp = q_sh + half * 100;
    float sv = 0.f;
#pragma unroll 4
    for (int a = 0; a < 100; ++a) sv += kp[a] * qp[a];
    sv += __shfl_xor(sv, 1, 64);
    if (half == 0) a_sh[h] = sv * ATT_INV;
  }
  __syncthreads();
  if (tid < CATN) {
    float m = -3.4e38f;
    for (int h = 0; h < HH; ++h)
      if (c_sh[h] == tid) m = fmaxf(m, a_sh[h]);
    smax[tid] = m;
  }
  __syncthreads();
  if (tid < HH) a_sh[tid] = expf(a_sh[tid] - smax[c_sh[tid]]);
  __syncthreads();
  if (tid < CATN) {
    float dsum = 0.f;
    for (int h = 0; h < HH; ++h)
      if (c_sh[h] == tid) dsum += a_sh[h];
    sden[tid] = dsum;
  }
  __syncthreads();
  if (tid < HH) a_sh[tid] = a_sh[tid] / sden[c_sh[tid]];
  __syncthreads();
  for (int idx = tid; idx < CATN * 128; idx += 256) {
    int c = idx >> 7, h = idx & 127;
    float v = (h < HH && c_sh[h] == c) ? a_sh[h] : 0.f;
    P[((size_t)b * 320 + n * CATN + c) * 128 + h] = f2bf(v);
  }
}

// --------- fused scatter + affine + s-dot. Grid 640 = 64b x 10 row-chunks(32),
// b-chunked XCD. GEMM1 intra = P@gfT (K=128) -> LDS bf16 (invalid rows zeroed)
// -> GEMM2 @afWt (K=416) -> v = relu(+afb)+resid ; intra2B = bf16(v) ;
// s_pre[row] = (v . p) * ATT_INV
__global__ __launch_bounds__(256) void k_scaf(
    const unsigned short* __restrict__ P, const unsigned short* __restrict__ gfT,
    const unsigned short* __restrict__ afWt, const float* __restrict__ afb,
    const float* __restrict__ p, float* __restrict__ s_pre,
    unsigned short* __restrict__ intra2B) {
  __shared__ unsigned short o_sh[32 * 424];
  __shared__ float ps_sh[32][2];
  const int tid = threadIdx.x;
  const int g = (blockIdx.x & 7) * (gridDim.x >> 3) + (blockIdx.x >> 3);
  const int b = g / 10;
  const int r0p = (g - b * 10) * 32;   // panel row base (rows valid < 304)
  const int lane = tid & 63, w = tid >> 6;
  const int lrow = lane & 15, lk = lane >> 4;
  const int rg = w & 1, nh = w >> 1;
  const int cbeg = nh * 13;
  const int r0 = rg * 16 + lk * 4;
  // --- GEMM1: intra = P @ gf ---
  {
    f32x4 acc[13];
#pragma unroll
    for (int c = 0; c < 13; ++c) acc[c] = f32x4{0.f, 0.f, 0.f, 0.f};
    const unsigned short* ap = &P[((size_t)b * 320 + r0p + rg * 16 + lrow) * 128 + lk * 8];
    const unsigned short* wp = &gfT[((size_t)b * 416 + cbeg * 16 + lrow) * 128 + lk * 8];
    for (int ks = 0; ks < 4; ++ks) {
      s16x8 af = *reinterpret_cast<const s16x8*>(ap + ks * 32);
#pragma unroll
      for (int c = 0; c < 13; ++c) {
        s16x8 bf = *reinterpret_cast<const s16x8*>(wp + (size_t)c * 16 * 128 + ks * 32);
        acc[c] = __builtin_amdgcn_mfma_f32_16x16x32_bf16(af, bf, acc[c], 0, 0, 0);
      }
    }
    // stage; rows >= 304 carry garbage-P NaN -> zero them (and K-pad cols)
#pragma unroll
    for (int c = 0; c < 13; ++c) {
      int col = (cbeg + c) * 16 + lrow;
#pragma unroll
      for (int j = 0; j < 4; ++j) {
        int pr = r0p + r0 + j;
        o_sh[(r0 + j) * 424 + col] = f2bf((pr < 304 && col < DD) ? acc[c][j] : 0.f);
      }
    }
  }
  __syncthreads();
  // --- GEMM2: o_sh @ afWt ---
  f32x4 acc2[13];
#pragma unroll
  for (int c = 0; c < 13; ++c) acc2[c] = f32x4{0.f, 0.f, 0.f, 0.f};
  {
    const unsigned short* ap = &o_sh[(rg * 16 + lrow) * 424 + lk * 8];
    const unsigned short* wp = &afWt[((size_t)(cbeg * 16) + lrow) * 416 + lk * 8];
    for (int ks = 0; ks < 13; ++ks) {
      s16x8 af = *reinterpret_cast<const s16x8*>(ap + ks * 32);
#pragma unroll
      for (int c = 0; c < 13; ++c) {
        s16x8 bf = *reinterpret_cast<const s16x8*>(wp + (size_t)c * 16 * 416 + ks * 32);
        acc2[c] = __builtin_amdgcn_mfma_f32_16x16x32_bf16(af, bf, acc2[c], 0, 0, 0);
      }
    }
  }
  // --- epilogue: relu+resid, store bf16, fused s-dot ---
  const float* prow[4];
#pragma unroll
  for (int j = 0; j < 4; ++j) {
    int prc = r0p + r0 + j;
    if (prc > 303) prc = 303;
    prow[j] = p + (size_t)(b * 16 + prc / CATN) * DD;
  }
  float sp[4] = {0.f, 0.f, 0.f, 0.f};
#pragma unroll
  for (int c = 0; c < 13; ++c) {
    int col = (cbeg + c) * 16 + lrow;
    if (col < DD) {
      float bv = afb[col];
#pragma unroll
      for (int j = 0; j < 4; ++j) {
        int pr = r0p + r0 + j;
        if (pr < 304) {
          size_t grow = (size_t)b * 304 + pr;
          float v = fmaxf(acc2[c][j] + bv, 0.f) + bf2f(o_sh[(r0 + j) * 424 + col]);
          intra2B[grow * 416 + col] = f2bf(v);
          sp[j] += v * prow[j][col];
        }
      }
    }
  }
#pragma unroll
  for (int j = 0; j < 4; ++j) {
    sp[j] += __shfl_xor(sp[j], 1, 64);
    sp[j] += __shfl_xor(sp[j], 2, 64);
    sp[j] += __shfl_xor(sp[j], 4, 64);
    sp[j] += __shfl_xor(sp[j], 8, 64);
  }
  if (lrow == 0) {
#pragma unroll
    for (int j = 0; j < 4; ++j) ps_sh[r0 + j][nh] = sp[j];
  }
  __syncthreads();
  if (tid < 32 && r0p + tid < 304)
    s_pre[(size_t)b * 304 + r0p + tid] = (ps_sh[tid][0] + ps_sh[tid][1]) * ATT_INV;
}

// --------- masked softmax over 19 (s_pre precomputed) ; out = sum_c w*intra2
__global__ __launch_bounds__(256) void k_final(const unsigned short* __restrict__ intra2B,
    const float* __restrict__ s_pre, const int* __restrict__ mask,
    float* __restrict__ out) {
  __shared__ float w_sh[CATN];
  const int i = blockIdx.x;
  const int xcd = i & 7, s = i >> 3;
  const int b = 8 * xcd + (s >> 4);
  const int n = s & 15;
  const int bn = b * 16 + n;
  const int tid = threadIdx.x;
  if (tid == 0) {
    float sv[CATN];
    float mx = -3.4e38f;
#pragma unroll
    for (int c = 0; c < CATN; ++c) {
      bool mk = (c == CATN - 1) || (mask[b * CATN + c] != 0);
      float sc = mk ? s_pre[bn * CATN + c] : -3.4e38f;
      sv[c] = sc;
      mx = fmaxf(mx, sc);
    }
    float den = 0.f;
#pragma unroll
    for (int c = 0; c < CATN; ++c) {
      float e = (sv[c] <= -3.3e38f) ? 0.f : expf(sv[c] - mx);
      w_sh[c] = e;
      den += e;
    }
    float inv = 1.0f / den;
#pragma unroll
    for (int c = 0; c < CATN; ++c) w_sh[c] *= inv;
  }
  __syncthreads();
  const unsigned short* ib = intra2B + (size_t)bn * CATN * 416;
  for (int d = tid; d < DD; d += 256) {
    float o = 0.f;
#pragma unroll
    for (int c = 0; c < CATN; ++c) o += w_sh[c] * bf2f(ib[c * 416 + d]);
    out[(size_t)bn * DD + d] = o;
  }
}

// ============================================================================
extern "C" void kernel_launch(void* const* d_in, const int* in_sizes, int n_in,
                              void* d_out, int out_size, void* d_ws, size_t ws_size,
                              hipStream_t stream) {
  const float* hist  = (const float*)d_in[0];
  const float* cand  = (const float*)d_in[1];
  const float* G     = (const float*)d_in[2];
  const int*   cmask = (const int*)d_in[3];
  const int*   cidx  = (const int*)d_in[4];
  const float* proxy = (const float*)d_in[5];
  const float* gW    = (const float*)d_in[6];
  const float* gb    = (const float*)d_in[7];
  const float* lns   = (const float*)d_in[8];
  const float* lnb   = (const float*)d_in[9];
  const float* Kw    = (const float*)d_in[10];
  const float* Qw    = (const float*)d_in[11];
  const float* Qbb   = (const float*)d_in[12];
  const float* afW   = (const float*)d_in[13];
  const float* afb   = (const float*)d_in[14];
  const float* icKw  = (const float*)d_in[15];
  const float* icQw  = (const float*)d_in[16];
  const float* icQb  = (const float*)d_in[17];
  float* out = (float*)d_out;
  float* ws  = (float*)d_ws;

  // ---- workspace layout (float offsets) ----
  // he      @0          3,020,800  (-> Pbuf/qbuf/pbuf/s_pre after toT_gf)
  // s1      @3,020,800  3,020,800  (h1/h2 -> Kbuf)
  // s2f     @6,041,600  3,020,800  (gf fp32 [6400][400])
  // TB      @9,062,400  1,703,936  ([64][416][128] bf16)
  // intra2B @14,813,184 4,046,848  (bf16 [19456][416])
  // wbase   @18,860,032   525,824 ; bias3 @19,385,856 (608)
  float* he    = ws;
  float* s1    = ws + 3020800;
  float* s2f   = ws + 6041600;
  unsigned short* TB     = (unsigned short*)(ws + 9062400);
  unsigned short* intra2B= (unsigned short*)(ws + 14813184);
  unsigned short* wbase  = (unsigned short*)(ws + 18860032);
  float* bias3 = ws + 19385856;
  unsigned short* Pbuf = (unsigned short*)ws;
  float* qbuf  = ws + 1310720;                  // [1024][200]
  float* pbuf  = ws + 1515520;                  // [1024][400]
  float* s_pre = ws + 1925120;                  // [19456]
  float* Kbuf  = s1;
  unsigned short* gW0t  = wbase;
  unsigned short* gW1t  = wbase + 173056;
  unsigned short* afWt  = wbase + 346112;
  unsigned short* Kwt   = wbase + 519168;       // [224][416]
  unsigned short* icKwB = wbase + 612352;       // [416][224]
  unsigned short* icQwB = wbase + 705536;       // [416][224]
  unsigned short* Wqp   = wbase + 798720;       // [608][416]

  // 0. weight prep + fused icQ->p matrix
  k_prep_all<<<3461, 256, 0, stream>>>(gW, afW, Kw, Qw, icQw, icKw, Qbb, icQb, wbase, bias3);
  k_prep_M<<<13, 256, 0, stream>>>(icKwB, icQwB, Wqp);
  // 1. fused concat + transpose: he + hT
  k_toT_he<<<448, 256, 0, stream>>>(hist, proxy, he, TB);
  // 2. GCN layer 0 (fused graph-mm + dense-LN) -> s1
  k_gln<<<256, 256, 0, stream>>>(G, TB, he, gW0t, gb, lns, lnb, s1);
  // 3. transpose h1 -> TB
  k_toT<NODES><<<448, 256, 0, stream>>>(s1, TB);
  // 4. GCN layer 1 (in-place s1)
  k_gln<<<256, 256, 0, stream>>>(G, TB, s1, gW1t, gb + DD, lns + DD, lnb + DD, s1);
  // 5. fused gf = (h2+he)[:, :HH] + transpose: gf + gfT
  k_toT_gf<<<448, 256, 0, stream>>>(s1, he, s2f, TB);
  // 6. K = gf @ Kw -> Kbuf (grid 200 %8==0)
  k_mg<400, 416, 200, 0><<<BH / 32, 256, 0, stream>>>(s2f, Kwt, nullptr, Kbuf, nullptr);
  // 7. fused Q-proj + p-proj (grid 32 %8==0)
  k_mg<400, 416, 608, 6><<<BB * NN / 32, 256, 0, stream>>>(cand, Wqp, bias3, qbuf, pbuf);
  // 8. alpha -> P (b-chunked XCD)
  k_palpha<<<BB * NN, 256, 0, stream>>>(Kbuf, qbuf, cidx, Pbuf);
  // 9. fused scatter + affine + s-dot -> intra2B, s_pre (grid 640, b-chunked)
  k_scaf<<<640, 256, 0, stream>>>(Pbuf, TB, afWt, afb, pbuf, s_pre, intra2B);
  // 10. final softmax + weighted sum (b-chunked XCD)
  k_final<<<BB * NN, 256, 0, stream>>>(intra2B, s_pre, cmask, out);
}

// Round 12
// 338.437 us; speedup vs baseline: 1.3396x; 1.3396x over previous
//
#include <hip/hip_runtime.h>
#include <hip/hip_bf16.h>
#include <math.h>

#define BB 64
#define NN 16
#define HH 100
#define DD 400
#define AA 200
#define CATN 19
#define NODES 118            // HH + CATN-1
#define BN (BB*NODES)        // 7552
#define BH (BB*HH)           // 6400
#define ATT_INV 0.07071067811865475f   // 1/sqrt(200)

typedef __attribute__((ext_vector_type(4))) float f32x4;
typedef __attribute__((ext_vector_type(8))) short s16x8;

__device__ __forceinline__ unsigned short f2bf(float f) {
  union { float f; unsigned int u; } v; v.f = f;
  unsigned int r = v.u + 0x7FFFu + ((v.u >> 16) & 1u);
  return (unsigned short)(r >> 16);
}
__device__ __forceinline__ float bf2f(unsigned short u) {
  union { unsigned int i; float f; } v; v.i = ((unsigned int)u) << 16; return v.f;
}

// ---------------- fused concat + transpose: he fp32 + hT bf16 [b][416][128]
__global__ __launch_bounds__(256) void k_toT_he(const float* __restrict__ hist,
    const float* __restrict__ proxy, float* __restrict__ he,
    unsigned short* __restrict__ T) {
  __shared__ float t_sh[64][129];
  const int b = blockIdx.x / 7, dt = blockIdx.x % 7;
  const int d0 = dt * 64;
  const int tid = threadIdx.x;
  const int dc = tid & 63, jr = tid >> 6;
  for (int j0 = 0; j0 < 128; j0 += 4) {
    int j = j0 + jr, d = d0 + dc;
    float v = 0.f;
    if (j < NODES && d < DD) {
      v = (j < HH) ? hist[((size_t)b * HH + j) * DD + d]
                   : proxy[(size_t)(j - HH) * DD + d];
      he[((size_t)b * NODES + j) * DD + d] = v;
    }
    t_sh[dc][j] = v;
  }
  __syncthreads();
  const int jc = tid & 127, dr2 = tid >> 7;
  for (int di = 0; di < 64; di += 2) {
    int dr = di + dr2;
    int d = d0 + dr;
    if (d < 416) T[((size_t)b * 416 + d) * 128 + jc] = f2bf(t_sh[dr][jc]);
  }
}

// ---------------- transpose h[b][RPB][400] fp32 -> T[b][416][128] bf16
template<int RPB>
__global__ __launch_bounds__(256) void k_toT(const float* __restrict__ h,
    unsigned short* __restrict__ T) {
  __shared__ float t_sh[64][129];
  const int b = blockIdx.x / 7, dt = blockIdx.x % 7;
  const int d0 = dt * 64;
  const int tid = threadIdx.x;
  const int dc = tid & 63, jr = tid >> 6;
  for (int j0 = 0; j0 < 128; j0 += 4) {
    int j = j0 + jr, d = d0 + dc;
    float v = (j < RPB && d < DD) ? h[((size_t)b * RPB + j) * DD + d] : 0.f;
    t_sh[dc][j] = v;
  }
  __syncthreads();
  const int jc = tid & 127, dr2 = tid >> 7;
  for (int di = 0; di < 64; di += 2) {
    int dr = di + dr2;
    int d = d0 + dr;
    if (d < 416) T[((size_t)b * 416 + d) * 128 + jc] = f2bf(t_sh[dr][jc]);
  }
}

// ---------------- fused gf = (h2+he)[:, :HH] + transpose -> gf fp32 + gfT bf16
__global__ __launch_bounds__(256) void k_toT_gf(const float* __restrict__ h2,
    const float* __restrict__ he, float* __restrict__ gf,
    unsigned short* __restrict__ T) {
  __shared__ float t_sh[64][129];
  const int b = blockIdx.x / 7, dt = blockIdx.x % 7;
  const int d0 = dt * 64;
  const int tid = threadIdx.x;
  const int dc = tid & 63, jr = tid >> 6;
  for (int j0 = 0; j0 < 128; j0 += 4) {
    int j = j0 + jr, d = d0 + dc;
    float v = 0.f;
    if (j < HH && d < DD) {
      size_t src = ((size_t)b * NODES + j) * DD + d;
      v = h2[src] + he[src];
      gf[((size_t)b * HH + j) * DD + d] = v;
    }
    t_sh[dc][j] = v;
  }
  __syncthreads();
  const int jc = tid & 127, dr2 = tid >> 7;
  for (int di = 0; di < 64; di += 2) {
    int dr = di + dr2;
    int d = d0 + dr;
    if (d < 416) T[((size_t)b * 416 + d) * 128 + jc] = f2bf(t_sh[dr][jc]);
  }
}

// ---------------- graph MFMA: tmpb[b][i][0..415] = bf16( G[b] @ h[b] )
__global__ __launch_bounds__(256) void k_gmm(const float* __restrict__ G,
    const unsigned short* __restrict__ hT, unsigned short* __restrict__ tmpb) {
  __shared__ unsigned short a_sh[32 * 136];
  const int b = blockIdx.x >> 2;
  const int i0 = (blockIdx.x & 3) * 32;
  const int tid = threadIdx.x;
  for (int idx = tid; idx < 32 * 128; idx += 256) {
    int r = idx >> 7, j = idx & 127;
    int i = i0 + r;
    float v = (i < NODES && j < NODES) ? G[((size_t)b * NODES + i) * NODES + j] : 0.f;
    a_sh[r * 136 + j] = f2bf(v);
  }
  __syncthreads();
  const int lane = tid & 63, w = tid >> 6;
  const int lrow = lane & 15, lk = lane >> 4;
  const int rg = w & 1, nh = w >> 1;
  const int cbeg = nh * 13;
  f32x4 acc[13];
#pragma unroll
  for (int c = 0; c < 13; ++c) acc[c] = f32x4{0.f, 0.f, 0.f, 0.f};
  const unsigned short* ap = &a_sh[(rg * 16 + lrow) * 136 + lk * 8];
  const unsigned short* wp = &hT[((size_t)b * 416 + cbeg * 16 + lrow) * 128 + lk * 8];
  for (int ks = 0; ks < 4; ++ks) {
    s16x8 af = *reinterpret_cast<const s16x8*>(ap + ks * 32);
#pragma unroll
    for (int c = 0; c < 13; ++c) {
      s16x8 bf = *reinterpret_cast<const s16x8*>(wp + (size_t)c * 16 * 128 + ks * 32);
      acc[c] = __builtin_amdgcn_mfma_f32_16x16x32_bf16(af, bf, acc[c], 0, 0, 0);
    }
  }
  const int r0 = rg * 16 + lk * 4;
#pragma unroll
  for (int c = 0; c < 13; ++c) {
    int col = (cbeg + c) * 16 + lrow;
#pragma unroll
    for (int j = 0; j < 4; ++j) {
      int i = i0 + r0 + j;
      if (i < NODES)
        tmpb[((size_t)b * NODES + i) * 416 + col] = f2bf(acc[c][j]);
    }
  }
}

// ---------------- dense LN GEMM (quarter-split): bf16 A direct-global.
// 4 waves = 4 N-quarters (7 frags, static; frags with col>=400 discarded),
// each wave computes BOTH 16-row groups (B reuse 2x).
// out = LN(relu(A@W+b)+resid)
__global__ __launch_bounds__(256) void k_mgb_ln(
    const unsigned short* __restrict__ A, const unsigned short* __restrict__ Wt,
    const float* __restrict__ bias, const float* __restrict__ resid,
    const float* __restrict__ lns, const float* __restrict__ lnb,
    float* __restrict__ out) {
  __shared__ float ps_sh[32][4][2];
  const int tid = threadIdx.x;
  const size_t row0 = (size_t)blockIdx.x * 32;
  const int lane = tid & 63, w = tid >> 6;
  const int lrow = lane & 15, lk = lane >> 4;
  const int cbeg = w * 7;
  f32x4 acc0[7], acc1[7];
#pragma unroll
  for (int c = 0; c < 7; ++c) {
    acc0[c] = f32x4{0.f, 0.f, 0.f, 0.f};
    acc1[c] = f32x4{0.f, 0.f, 0.f, 0.f};
  }
  const unsigned short* ap0 = &A[(row0 + lrow) * 416 + lk * 8];
  const unsigned short* ap1 = ap0 + 16 * 416;
  const unsigned short* wp = &Wt[((size_t)(cbeg * 16) + lrow) * 416 + lk * 8];
  for (int ks = 0; ks < 13; ++ks) {
    s16x8 af0 = *reinterpret_cast<const s16x8*>(ap0 + ks * 32);
    s16x8 af1 = *reinterpret_cast<const s16x8*>(ap1 + ks * 32);
#pragma unroll
    for (int c = 0; c < 7; ++c) {
      s16x8 bf = *reinterpret_cast<const s16x8*>(wp + (size_t)c * 16 * 416 + ks * 32);
      acc0[c] = __builtin_amdgcn_mfma_f32_16x16x32_bf16(af0, bf, acc0[c], 0, 0, 0);
      acc1[c] = __builtin_amdgcn_mfma_f32_16x16x32_bf16(af1, bf, acc1[c], 0, 0, 0);
    }
  }
  float zs0[4], zq0[4], zs1[4], zq1[4];
#pragma unroll
  for (int j = 0; j < 4; ++j) { zs0[j] = zq0[j] = zs1[j] = zq1[j] = 0.f; }
#pragma unroll
  for (int c = 0; c < 7; ++c) {
    int col = (cbeg + c) * 16 + lrow;
    bool cv = col < DD;
    float bv = cv ? bias[col] : 0.f;
#pragma unroll
    for (int j = 0; j < 4; ++j) {
      size_t ra = row0 + lk * 4 + j;
      size_t rb = ra + 16;
      float z0 = 0.f, z1 = 0.f;
      if (cv) {
        z0 = fmaxf(acc0[c][j] + bv, 0.f) + resid[ra * (size_t)DD + col];
        z1 = fmaxf(acc1[c][j] + bv, 0.f) + resid[rb * (size_t)DD + col];
      }
      acc0[c][j] = z0; zs0[j] += z0; zq0[j] += z0 * z0;
      acc1[c][j] = z1; zs1[j] += z1; zq1[j] += z1 * z1;
    }
  }
#pragma unroll
  for (int j = 0; j < 4; ++j) {
    zs0[j] += __shfl_xor(zs0[j], 1, 64); zq0[j] += __shfl_xor(zq0[j], 1, 64);
    zs0[j] += __shfl_xor(zs0[j], 2, 64); zq0[j] += __shfl_xor(zq0[j], 2, 64);
    zs0[j] += __shfl_xor(zs0[j], 4, 64); zq0[j] += __shfl_xor(zq0[j], 4, 64);
    zs0[j] += __shfl_xor(zs0[j], 8, 64); zq0[j] += __shfl_xor(zq0[j], 8, 64);
    zs1[j] += __shfl_xor(zs1[j], 1, 64); zq1[j] += __shfl_xor(zq1[j], 1, 64);
    zs1[j] += __shfl_xor(zs1[j], 2, 64); zq1[j] += __shfl_xor(zq1[j], 2, 64);
    zs1[j] += __shfl_xor(zs1[j], 4, 64); zq1[j] += __shfl_xor(zq1[j], 4, 64);
    zs1[j] += __shfl_xor(zs1[j], 8, 64); zq1[j] += __shfl_xor(zq1[j], 8, 64);
  }
  if (lrow == 0) {
#pragma unroll
    for (int j = 0; j < 4; ++j) {
      ps_sh[lk * 4 + j][w][0] = zs0[j];
      ps_sh[lk * 4 + j][w][1] = zq0[j];
      ps_sh[16 + lk * 4 + j][w][0] = zs1[j];
      ps_sh[16 + lk * 4 + j][w][1] = zq1[j];
    }
  }
  __syncthreads();
  float mu0[4], rs0[4], mu1[4], rs1[4];
#pragma unroll
  for (int j = 0; j < 4; ++j) {
    int la = lk * 4 + j, lb = la + 16;
    float s0 = ps_sh[la][0][0] + ps_sh[la][1][0] + ps_sh[la][2][0] + ps_sh[la][3][0];
    float q0 = ps_sh[la][0][1] + ps_sh[la][1][1] + ps_sh[la][2][1] + ps_sh[la][3][1];
    mu0[j] = s0 * (1.0f / DD);
    rs0[j] = 1.0f / sqrtf(q0 * (1.0f / DD) - mu0[j] * mu0[j] + 1e-5f);
    float s1v = ps_sh[lb][0][0] + ps_sh[lb][1][0] + ps_sh[lb][2][0] + ps_sh[lb][3][0];
    float q1v = ps_sh[lb][0][1] + ps_sh[lb][1][1] + ps_sh[lb][2][1] + ps_sh[lb][3][1];
    mu1[j] = s1v * (1.0f / DD);
    rs1[j] = 1.0f / sqrtf(q1v * (1.0f / DD) - mu1[j] * mu1[j] + 1e-5f);
  }
#pragma unroll
  for (int c = 0; c < 7; ++c) {
    int col = (cbeg + c) * 16 + lrow;
    if (col < DD) {
      float sc = lns[col], bo = lnb[col];
#pragma unroll
      for (int j = 0; j < 4; ++j) {
        size_t ra = row0 + lk * 4 + j;
        out[ra * (size_t)DD + col] = (acc0[c][j] - mu0[j]) * rs0[j] * sc + bo;
        out[(ra + 16) * (size_t)DD + col] = (acc1[c][j] - mu1[j]) * rs1[j] * sc + bo;
      }
    }
  }
}

// ---------------- one-shot weight prep (bf16 transposed+padded blobs)
__global__ __launch_bounds__(256) void k_prep_all(const float* __restrict__ gW,
    const float* __restrict__ afW, const float* __restrict__ Kw,
    const float* __restrict__ Qw, const float* __restrict__ icQw,
    const float* __restrict__ icKw, const float* __restrict__ Qb,
    const float* __restrict__ icQb, unsigned short* __restrict__ wbase,
    float* __restrict__ bias3) {
  int idx = blockIdx.x * 256 + threadIdx.x;
  const int SG = 416 * 416;   // 173056
  const int SK = 224 * 416;   // 93184
  if (idx < SG) {             // gW0t
    int n = idx / 416, k = idx - n * 416;
    wbase[idx] = (n < 400 && k < 400) ? f2bf(gW[(size_t)k * 400 + n]) : (unsigned short)0;
    return;
  }
  idx -= SG;
  if (idx < SG) {             // gW1t
    int n = idx / 416, k = idx - n * 416;
    wbase[173056 + idx] = (n < 400 && k < 400) ? f2bf(gW[160000 + (size_t)k * 400 + n]) : (unsigned short)0;
    return;
  }
  idx -= SG;
  if (idx < SG) {             // afWt
    int n = idx / 416, k = idx - n * 416;
    wbase[346112 + idx] = (n < 400 && k < 400) ? f2bf(afW[(size_t)k * 400 + n]) : (unsigned short)0;
    return;
  }
  idx -= SG;
  if (idx < SK) {             // Kwt [224 n][416 k]
    int n = idx / 416, k = idx - n * 416;
    wbase[519168 + idx] = (n < 200 && k < 400) ? f2bf(Kw[(size_t)k * 200 + n]) : (unsigned short)0;
    return;
  }
  idx -= SK;
  if (idx < SK) {             // icKwB [416 d][224 a]
    int d = idx / 224, a = idx - d * 224;
    wbase[612352 + idx] = (d < 400 && a < 200) ? f2bf(icKw[(size_t)d * 200 + a]) : (unsigned short)0;
    return;
  }
  idx -= SK;
  if (idx < SK) {             // icQwB [416 k][224 a]
    int k = idx / 224, a = idx - k * 224;
    wbase[705536 + idx] = (k < 400 && a < 200) ? f2bf(icQw[(size_t)k * 200 + a]) : (unsigned short)0;
    return;
  }
  idx -= SK;
  if (idx < 208 * 416) {      // Wqp rows 0..207 (Q part)
    int n = idx / 416, k = idx - n * 416;
    wbase[798720 + idx] = (n < 200 && k < 400) ? f2bf(Qw[(size_t)k * 200 + n]) : (unsigned short)0;
    return;
  }
  idx -= 208 * 416;
  if (idx < 608) {            // bias3
    float v = 0.f;
    if (idx < 200) v = Qb[idx];
    else if (idx >= 208) {
      const float* kr = icKw + (size_t)(idx - 208) * 200;
      float s = 0.f;
      for (int a = 0; a < 200; ++a) s += icQb[a] * kr[a];
      v = s;
    }
    bias3[idx] = v;
  }
}

// ---------------- M-prep: Wqp[208+d][k] = bf16( sum_a icKw[d,a]*icQw[k,a] ), MFMA
__global__ __launch_bounds__(256) void k_prep_M(const unsigned short* __restrict__ icKwB,
    const unsigned short* __restrict__ icQwB, unsigned short* __restrict__ wqp) {
  const int tid = threadIdx.x;
  const size_t row0 = (size_t)blockIdx.x * 32;
  const int lane = tid & 63, w = tid >> 6;
  const int lrow = lane & 15, lk = lane >> 4;
  const int rg = w & 1, nh = w >> 1;
  const int cbeg = nh * 13;
  f32x4 acc[13];
#pragma unroll
  for (int c = 0; c < 13; ++c) acc[c] = f32x4{0.f, 0.f, 0.f, 0.f};
  const unsigned short* ap = &icKwB[(row0 + rg * 16 + lrow) * 224 + lk * 8];
  const unsigned short* bp = &icQwB[((size_t)(cbeg * 16) + lrow) * 224 + lk * 8];
  for (int ks = 0; ks < 7; ++ks) {
    s16x8 af = *reinterpret_cast<const s16x8*>(ap + ks * 32);
#pragma unroll
    for (int c = 0; c < 13; ++c) {
      s16x8 bf = *reinterpret_cast<const s16x8*>(bp + (size_t)c * 16 * 224 + ks * 32);
      acc[c] = __builtin_amdgcn_mfma_f32_16x16x32_bf16(af, bf, acc[c], 0, 0, 0);
    }
  }
  const int r0 = rg * 16 + lk * 4;
#pragma unroll
  for (int c = 0; c < 13; ++c) {
    int k = (cbeg + c) * 16 + lrow;
#pragma unroll
    for (int j = 0; j < 4; ++j) {
      size_t d = row0 + r0 + j;
      if (d < 400) wqp[(208 + d) * 416 + k] = f2bf(acc[c][j]);
    }
  }
}

// =================== fp32-A MFMA GEMM (v1 decomposition, XCD row-chunk swizzle)
// EPI: 0 plain(colguard), 6 QP dual-output.
template<int KDIM, int KPAD, int NOUT, int EPI>
__global__ __launch_bounds__(256) void k_mg(
    const float* __restrict__ A, const unsigned short* __restrict__ Wt,
    const float* __restrict__ bias, float* __restrict__ out, float* __restrict__ out2) {
  constexpr int APITCH = KPAD + 8;
  constexpr int NF = (NOUT + 15) / 16;
  constexpr int NF0 = (NF + 1) / 2;
  constexpr int KS = KPAD / 32;
  constexpr int E4 = KDIM / 4;
  constexpr int PADN = KPAD - KDIM;
  __shared__ unsigned short a_sh[32 * APITCH];
  const int tid = threadIdx.x;
  const int g = (blockIdx.x % 8) * (gridDim.x / 8) + blockIdx.x / 8;
  const size_t row0 = (size_t)g * 32;
  for (int i = tid; i < 32 * E4; i += 256) {
    int r = i / E4, c4 = i - r * E4;
    const float4 v = *reinterpret_cast<const float4*>(&A[(row0 + r) * (size_t)KDIM + c4 * 4]);
    unsigned int lo = (unsigned int)f2bf(v.x) | ((unsigned int)f2bf(v.y) << 16);
    unsigned int hi = (unsigned int)f2bf(v.z) | ((unsigned int)f2bf(v.w) << 16);
    *reinterpret_cast<uint2*>(&a_sh[r * APITCH + c4 * 4]) = make_uint2(lo, hi);
  }
  for (int i = tid; i < 32 * PADN; i += 256) {
    int r = i / PADN, c = i - r * PADN;
    a_sh[r * APITCH + KDIM + c] = 0;
  }
  __syncthreads();
  const int lane = tid & 63, w = tid >> 6;
  const int lrow = lane & 15, lk = lane >> 4;
  const int rg = w & 1, nh = w >> 1;
  const int cbeg = nh * NF0;
  f32x4 acc[NF0];
#pragma unroll
  for (int c = 0; c < NF0; ++c) acc[c] = f32x4{0.f, 0.f, 0.f, 0.f};
  const unsigned short* ap = &a_sh[(rg * 16 + lrow) * APITCH + lk * 8];
  const unsigned short* wp = &Wt[((size_t)(cbeg * 16) + lrow) * KPAD + lk * 8];
  for (int ks = 0; ks < KS; ++ks) {
    s16x8 af = *reinterpret_cast<const s16x8*>(ap + ks * 32);
#pragma unroll
    for (int c = 0; c < NF0; ++c) {
      s16x8 bf = *reinterpret_cast<const s16x8*>(wp + (size_t)c * 16 * KPAD + ks * 32);
      acc[c] = __builtin_amdgcn_mfma_f32_16x16x32_bf16(af, bf, acc[c], 0, 0, 0);
    }
  }
  const int r0 = rg * 16 + lk * 4;
  if (EPI == 0) {
#pragma unroll
    for (int c = 0; c < NF0; ++c) {
      int col = (cbeg + c) * 16 + lrow;
      if (col < NOUT) {
#pragma unroll
        for (int j = 0; j < 4; ++j)
          out[(row0 + r0 + j) * (size_t)NOUT + col] = acc[c][j];
      }
    }
  } else {  // EPI == 6
#pragma unroll
    for (int c = 0; c < NF0; ++c) {
      int col = (cbeg + c) * 16 + lrow;
      if (col < 200) {
        float bv = bias[col];
#pragma unroll
        for (int j = 0; j < 4; ++j)
          out[(row0 + r0 + j) * (size_t)AA + col] = acc[c][j] + bv;
      } else if (col >= 208 && col < 608) {
        float bv = bias[col];
#pragma unroll
        for (int j = 0; j < 4; ++j)
          out2[(row0 + r0 + j) * (size_t)DD + (col - 208)] = acc[c][j] + bv;
      }
    }
  }
}

// --------- alpha segment-softmax -> P bf16 [b][320 pitch][128]  (b-chunked XCD)
__global__ __launch_bounds__(256) void k_palpha(const float* __restrict__ K,
    const float* __restrict__ Q, const int* __restrict__ cat,
    unsigned short* __restrict__ P) {
  __shared__ float q_sh[AA];
  __shared__ float a_sh[HH];
  __shared__ int c_sh[HH];
  __shared__ float smax[CATN], sden[CATN];
  const int i = blockIdx.x;
  const int xcd = i & 7, s = i >> 3;
  const int b = 8 * xcd + (s >> 4);
  const int n = s & 15;
  const int bn = b * 16 + n;
  const int tid = threadIdx.x;
  if (tid < AA) q_sh[tid] = Q[(size_t)bn * AA + tid];
  if (tid < HH) c_sh[tid] = cat[b * HH + tid];
  __syncthreads();
  if (tid < 2 * HH) {
    int h = tid >> 1, half = tid & 1;
    const float* kp = K + ((size_t)b * HH + h) * AA + half * 100;
    const float* qp = q_sh + half * 100;
    float sv = 0.f;
#pragma unroll 4
    for (int a = 0; a < 100; ++a) sv += kp[a] * qp[a];
    sv += __shfl_xor(sv, 1, 64);
    if (half == 0) a_sh[h] = sv * ATT_INV;
  }
  __syncthreads();
  if (tid < CATN) {
    float m = -3.4e38f;
    for (int h = 0; h < HH; ++h)
      if (c_sh[h] == tid) m = fmaxf(m, a_sh[h]);
    smax[tid] = m;
  }
  __syncthreads();
  if (tid < HH) a_sh[tid] = expf(a_sh[tid] - smax[c_sh[tid]]);
  __syncthreads();
  if (tid < CATN) {
    float dsum = 0.f;
    for (int h = 0; h < HH; ++h)
      if (c_sh[h] == tid) dsum += a_sh[h];
    sden[tid] = dsum;
  }
  __syncthreads();
  if (tid < HH) a_sh[tid] = a_sh[tid] / sden[c_sh[tid]];
  __syncthreads();
  for (int idx = tid; idx < CATN * 128; idx += 256) {
    int c = idx >> 7, h = idx & 127;
    float v = (h < HH && c_sh[h] == c) ? a_sh[h] : 0.f;
    P[((size_t)b * 320 + n * CATN + c) * 128 + h] = f2bf(v);
  }
}

// --------- scatter GEMM -> intraB bf16 [19456][416] (cols>=400 zeroed); b-chunked
__global__ __launch_bounds__(128) void k_sc(const unsigned short* __restrict__ P,
    const unsigned short* __restrict__ gfT, unsigned short* __restrict__ intraB) {
  const int i = blockIdx.x;
  const int xcd = i & 7, s = i >> 3;
  const int b = 8 * xcd + s / CATN;
  const int t = s % CATN;
  const int tid = threadIdx.x;
  const int lane = tid & 63, w = tid >> 6;
  const int lrow = lane & 15, lk = lane >> 4;
  const int cbeg = w * 13;
  f32x4 acc[13];
#pragma unroll
  for (int c = 0; c < 13; ++c) acc[c] = f32x4{0.f, 0.f, 0.f, 0.f};
  const unsigned short* ap = &P[((size_t)b * 320 + t * 16 + lrow) * 128 + lk * 8];
  const unsigned short* wp = &gfT[((size_t)b * 416 + cbeg * 16 + lrow) * 128 + lk * 8];
  for (int ks = 0; ks < 4; ++ks) {
    s16x8 af = *reinterpret_cast<const s16x8*>(ap + ks * 32);
#pragma unroll
    for (int c = 0; c < 13; ++c) {
      s16x8 bf = *reinterpret_cast<const s16x8*>(wp + (size_t)c * 16 * 128 + ks * 32);
      acc[c] = __builtin_amdgcn_mfma_f32_16x16x32_bf16(af, bf, acc[c], 0, 0, 0);
    }
  }
  const int r0 = lk * 4;
#pragma unroll
  for (int c = 0; c < 13; ++c) {
    int col = (cbeg + c) * 16 + lrow;
#pragma unroll
    for (int j = 0; j < 4; ++j)
      intraB[((size_t)b * 304 + t * 16 + r0 + j) * 416 + col] =
          f2bf(col < DD ? acc[c][j] : 0.f);
  }
}

// --------- affine GEMM v4 (quarter-split): 32-row tiles, grid 608.
// 4 waves = 4 N-quarters (7 frags static, col>=400 discarded), each wave
// computes BOTH row groups (B reuse 2x). bf16 A direct-global.
// v = relu(A@afW+b)+A ; intra2B = bf16(v) ; s_pre[row] = (v.p[row/19])*ATT_INV
__global__ __launch_bounds__(256) void k_afq(
    const unsigned short* __restrict__ A, const unsigned short* __restrict__ Wt,
    const float* __restrict__ bias, const float* __restrict__ p,
    float* __restrict__ s_pre, unsigned short* __restrict__ out2) {
  __shared__ float ps_sh[32][4];
  const int tid = threadIdx.x;
  const int g = (blockIdx.x % 8) * (gridDim.x / 8) + blockIdx.x / 8;
  const size_t row0 = (size_t)g * 32;
  const int lane = tid & 63, w = tid >> 6;
  const int lrow = lane & 15, lk = lane >> 4;
  const int cbeg = w * 7;
  f32x4 acc0[7], acc1[7];
#pragma unroll
  for (int c = 0; c < 7; ++c) {
    acc0[c] = f32x4{0.f, 0.f, 0.f, 0.f};
    acc1[c] = f32x4{0.f, 0.f, 0.f, 0.f};
  }
  const unsigned short* ap0 = &A[(row0 + lrow) * 416 + lk * 8];
  const unsigned short* ap1 = ap0 + 16 * 416;
  const unsigned short* wp = &Wt[((size_t)(cbeg * 16) + lrow) * 416 + lk * 8];
  for (int ks = 0; ks < 13; ++ks) {
    s16x8 af0 = *reinterpret_cast<const s16x8*>(ap0 + ks * 32);
    s16x8 af1 = *reinterpret_cast<const s16x8*>(ap1 + ks * 32);
#pragma unroll
    for (int c = 0; c < 7; ++c) {
      s16x8 bf = *reinterpret_cast<const s16x8*>(wp + (size_t)c * 16 * 416 + ks * 32);
      acc0[c] = __builtin_amdgcn_mfma_f32_16x16x32_bf16(af0, bf, acc0[c], 0, 0, 0);
      acc1[c] = __builtin_amdgcn_mfma_f32_16x16x32_bf16(af1, bf, acc1[c], 0, 0, 0);
    }
  }
  const float* prow0[4];
  const float* prow1[4];
#pragma unroll
  for (int j = 0; j < 4; ++j) {
    prow0[j] = p + (size_t)((row0 + lk * 4 + j) / CATN) * DD;
    prow1[j] = p + (size_t)((row0 + 16 + lk * 4 + j) / CATN) * DD;
  }
  float sp0[4] = {0.f, 0.f, 0.f, 0.f};
  float sp1[4] = {0.f, 0.f, 0.f, 0.f};
#pragma unroll
  for (int c = 0; c < 7; ++c) {
    int col = (cbeg + c) * 16 + lrow;
    if (col < DD) {
      float bv = bias[col];
#pragma unroll
      for (int j = 0; j < 4; ++j) {
        size_t ra = row0 + lk * 4 + j;
        float v0 = fmaxf(acc0[c][j] + bv, 0.f) + bf2f(A[ra * 416 + col]);
        out2[ra * 416 + col] = f2bf(v0);
        sp0[j] += v0 * prow0[j][col];
        size_t rb = ra + 16;
        float v1 = fmaxf(acc1[c][j] + bv, 0.f) + bf2f(A[rb * 416 + col]);
        out2[rb * 416 + col] = f2bf(v1);
        sp1[j] += v1 * prow1[j][col];
      }
    }
  }
#pragma unroll
  for (int j = 0; j < 4; ++j) {
    sp0[j] += __shfl_xor(sp0[j], 1, 64); sp1[j] += __shfl_xor(sp1[j], 1, 64);
    sp0[j] += __shfl_xor(sp0[j], 2, 64); sp1[j] += __shfl_xor(sp1[j], 2, 64);
    sp0[j] += __shfl_xor(sp0[j], 4, 64); sp1[j] += __shfl_xor(sp1[j], 4, 64);
    sp0[j] += __shfl_xor(sp0[j], 8, 64); sp1[j] += __shfl_xor(sp1[j], 8, 64);
  }
  if (lrow == 0) {
#pragma unroll
    for (int j = 0; j < 4; ++j) {
      ps_sh[lk * 4 + j][w] = sp0[j];
      ps_sh[16 + lk * 4 + j][w] = sp1[j];
    }
  }
  __syncthreads();
  if (tid < 32)
    s_pre[row0 + tid] =
        (ps_sh[tid][0] + ps_sh[tid][1] + ps_sh[tid][2] + ps_sh[tid][3]) * ATT_INV;
}

// --------- masked softmax over 19 (s_pre precomputed) ; out = sum_c w*intra2
__global__ __launch_bounds__(256) void k_final(const unsigned short* __restrict__ intra2B,
    const float* __restrict__ s_pre, const int* __restrict__ mask,
    float* __restrict__ out) {
  __shared__ float w_sh[CATN];
  const int i = blockIdx.x;
  const int xcd = i & 7, s = i >> 3;
  const int b = 8 * xcd + (s >> 4);
  const int n = s & 15;
  const int bn = b * 16 + n;
  const int tid = threadIdx.x;
  if (tid == 0) {
    float sv[CATN];
    float mx = -3.4e38f;
#pragma unroll
    for (int c = 0; c < CATN; ++c) {
      bool mk = (c == CATN - 1) || (mask[b * CATN + c] != 0);
      float sc = mk ? s_pre[bn * CATN + c] : -3.4e38f;
      sv[c] = sc;
      mx = fmaxf(mx, sc);
    }
    float den = 0.f;
#pragma unroll
    for (int c = 0; c < CATN; ++c) {
      float e = (sv[c] <= -3.3e38f) ? 0.f : expf(sv[c] - mx);
      w_sh[c] = e;
      den += e;
    }
    float inv = 1.0f / den;
#pragma unroll
    for (int c = 0; c < CATN; ++c) w_sh[c] *= inv;
  }
  __syncthreads();
  const unsigned short* ib = intra2B + (size_t)bn * CATN * 416;
  for (int d = tid; d < DD; d += 256) {
    float o = 0.f;
#pragma unroll
    for (int c = 0; c < CATN; ++c) o += w_sh[c] * bf2f(ib[c * 416 + d]);
    out[(size_t)bn * DD + d] = o;
  }
}

// ============================================================================
extern "C" void kernel_launch(void* const* d_in, const int* in_sizes, int n_in,
                              void* d_out, int out_size, void* d_ws, size_t ws_size,
                              hipStream_t stream) {
  const float* hist  = (const float*)d_in[0];
  const float* cand  = (const float*)d_in[1];
  const float* G     = (const float*)d_in[2];
  const int*   cmask = (const int*)d_in[3];
  const int*   cidx  = (const int*)d_in[4];
  const float* proxy = (const float*)d_in[5];
  const float* gW    = (const float*)d_in[6];
  const float* gb    = (const float*)d_in[7];
  const float* lns   = (const float*)d_in[8];
  const float* lnb   = (const float*)d_in[9];
  const float* Kw    = (const float*)d_in[10];
  const float* Qw    = (const float*)d_in[11];
  const float* Qbb   = (const float*)d_in[12];
  const float* afW   = (const float*)d_in[13];
  const float* afb   = (const float*)d_in[14];
  const float* icKw  = (const float*)d_in[15];
  const float* icQw  = (const float*)d_in[16];
  const float* icQb  = (const float*)d_in[17];
  float* out = (float*)d_out;
  float* ws  = (float*)d_ws;

  // ---- workspace layout (float offsets) ---- (same as round 10)
  float* he    = ws;
  float* s1    = ws + 3020800;
  float* s2f   = ws + 6041600;
  unsigned short* tmpb   = (unsigned short*)(ws + 6041600);
  unsigned short* TB     = (unsigned short*)(ws + 9062400);
  unsigned short* intraB = (unsigned short*)(ws + 10766336);
  unsigned short* intra2B= (unsigned short*)(ws + 14813184);
  unsigned short* wbase  = (unsigned short*)(ws + 18860032);
  float* bias3 = ws + 19385856;
  unsigned short* Pbuf = (unsigned short*)ws;
  float* qbuf  = ws + 1310720;                  // [1024][200]
  float* pbuf  = ws + 1515520;                  // [1024][400]
  float* s_pre = ws + 1925120;                  // [19456]
  float* Kbuf  = s1;
  unsigned short* gW0t  = wbase;
  unsigned short* gW1t  = wbase + 173056;
  unsigned short* afWt  = wbase + 346112;
  unsigned short* Kwt   = wbase + 519168;       // [224][416]
  unsigned short* icKwB = wbase + 612352;       // [416][224]
  unsigned short* icQwB = wbase + 705536;       // [416][224]
  unsigned short* Wqp   = wbase + 798720;       // [608][416]

  // 0. weight prep + fused icQ->p matrix
  k_prep_all<<<3461, 256, 0, stream>>>(gW, afW, Kw, Qw, icQw, icKw, Qbb, icQb, wbase, bias3);
  k_prep_M<<<13, 256, 0, stream>>>(icKwB, icQwB, Wqp);
  // 1. fused concat + transpose: he + hT
  k_toT_he<<<448, 256, 0, stream>>>(hist, proxy, he, TB);
  // 2-3. GCN layer 0
  k_gmm<<<256, 256, 0, stream>>>(G, TB, tmpb);
  k_mgb_ln<<<BN / 32, 256, 0, stream>>>(tmpb, gW0t, gb, he, lns, lnb, s1);
  // 4-6. GCN layer 1 (in-place s1)
  k_toT<NODES><<<448, 256, 0, stream>>>(s1, TB);
  k_gmm<<<256, 256, 0, stream>>>(G, TB, tmpb);
  k_mgb_ln<<<BN / 32, 256, 0, stream>>>(tmpb, gW1t, gb + DD, s1, lns + DD, lnb + DD, s1);
  // 7. fused gf = (h2+he)[:, :HH] + transpose: gf + gfT
  k_toT_gf<<<448, 256, 0, stream>>>(s1, he, s2f, TB);
  // 8. K = gf @ Kw -> Kbuf (grid 200 %8==0)
  k_mg<400, 416, 200, 0><<<BH / 32, 256, 0, stream>>>(s2f, Kwt, nullptr, Kbuf, nullptr);
  // 9. fused Q-proj + p-proj (grid 32 %8==0)
  k_mg<400, 416, 608, 6><<<BB * NN / 32, 256, 0, stream>>>(cand, Wqp, bias3, qbuf, pbuf);
  // 10. alpha -> P (b-chunked XCD)
  k_palpha<<<BB * NN, 256, 0, stream>>>(Kbuf, qbuf, cidx, Pbuf);
  // 11. intra = P @ gf -> intraB bf16 (b-chunked XCD)
  k_sc<<<BB * CATN, 128, 0, stream>>>(Pbuf, TB, intraB);
  // 12. affine v4 (quarter-split, grid 608) + fused s-dot -> intra2B, s_pre
  k_afq<<<BB * NN * CATN / 32, 256, 0, stream>>>(intraB, afWt, afb, pbuf, s_pre, intra2B);
  // 13. final softmax + weighted sum (b-chunked XCD)
  k_final<<<BB * NN, 256, 0, stream>>>(intra2B, s_pre, cmask, out);
}

// Round 13
// 311.493 us; speedup vs baseline: 1.4554x; 1.0865x over previous
//
#include <hip/hip_runtime.h>
#include <hip/hip_bf16.h>
#include <math.h>

#define BB 64
#define NN 16
#define HH 100
#define DD 400
#define AA 200
#define CATN 19
#define NODES 118            // HH + CATN-1
#define BN (BB*NODES)        // 7552
#define BH (BB*HH)           // 6400
#define ATT_INV 0.07071067811865475f   // 1/sqrt(200)

typedef __attribute__((ext_vector_type(4))) float f32x4;
typedef __attribute__((ext_vector_type(8))) short s16x8;

__device__ __forceinline__ unsigned short f2bf(float f) {
  union { float f; unsigned int u; } v; v.f = f;
  unsigned int r = v.u + 0x7FFFu + ((v.u >> 16) & 1u);
  return (unsigned short)(r >> 16);
}
__device__ __forceinline__ float bf2f(unsigned short u) {
  union { unsigned int i; float f; } v; v.i = ((unsigned int)u) << 16; return v.f;
}

// ---------------- fused concat + transpose: he fp32 + hT bf16 [b][416][128]
__global__ __launch_bounds__(256) void k_toT_he(const float* __restrict__ hist,
    const float* __restrict__ proxy, float* __restrict__ he,
    unsigned short* __restrict__ T) {
  __shared__ float t_sh[64][129];
  const int b = blockIdx.x / 7, dt = blockIdx.x % 7;
  const int d0 = dt * 64;
  const int tid = threadIdx.x;
  const int dc = tid & 63, jr = tid >> 6;
  for (int j0 = 0; j0 < 128; j0 += 4) {
    int j = j0 + jr, d = d0 + dc;
    float v = 0.f;
    if (j < NODES && d < DD) {
      v = (j < HH) ? hist[((size_t)b * HH + j) * DD + d]
                   : proxy[(size_t)(j - HH) * DD + d];
      he[((size_t)b * NODES + j) * DD + d] = v;
    }
    t_sh[dc][j] = v;
  }
  __syncthreads();
  const int jc = tid & 127, dr2 = tid >> 7;
  for (int di = 0; di < 64; di += 2) {
    int dr = di + dr2;
    int d = d0 + dr;
    if (d < 416) T[((size_t)b * 416 + d) * 128 + jc] = f2bf(t_sh[dr][jc]);
  }
}

// ---------------- transpose h[b][RPB][400] fp32 -> T[b][416][128] bf16
template<int RPB>
__global__ __launch_bounds__(256) void k_toT(const float* __restrict__ h,
    unsigned short* __restrict__ T) {
  __shared__ float t_sh[64][129];
  const int b = blockIdx.x / 7, dt = blockIdx.x % 7;
  const int d0 = dt * 64;
  const int tid = threadIdx.x;
  const int dc = tid & 63, jr = tid >> 6;
  for (int j0 = 0; j0 < 128; j0 += 4) {
    int j = j0 + jr, d = d0 + dc;
    float v = (j < RPB && d < DD) ? h[((size_t)b * RPB + j) * DD + d] : 0.f;
    t_sh[dc][j] = v;
  }
  __syncthreads();
  const int jc = tid & 127, dr2 = tid >> 7;
  for (int di = 0; di < 64; di += 2) {
    int dr = di + dr2;
    int d = d0 + dr;
    if (d < 416) T[((size_t)b * 416 + d) * 128 + jc] = f2bf(t_sh[dr][jc]);
  }
}

// ---------------- fused gf = (h2+he)[:, :HH] + transpose -> gf fp32 + gfT bf16
__global__ __launch_bounds__(256) void k_toT_gf(const float* __restrict__ h2,
    const float* __restrict__ he, float* __restrict__ gf,
    unsigned short* __restrict__ T) {
  __shared__ float t_sh[64][129];
  const int b = blockIdx.x / 7, dt = blockIdx.x % 7;
  const int d0 = dt * 64;
  const int tid = threadIdx.x;
  const int dc = tid & 63, jr = tid >> 6;
  for (int j0 = 0; j0 < 128; j0 += 4) {
    int j = j0 + jr, d = d0 + dc;
    float v = 0.f;
    if (j < HH && d < DD) {
      size_t src = ((size_t)b * NODES + j) * DD + d;
      v = h2[src] + he[src];
      gf[((size_t)b * HH + j) * DD + d] = v;
    }
    t_sh[dc][j] = v;
  }
  __syncthreads();
  const int jc = tid & 127, dr2 = tid >> 7;
  for (int di = 0; di < 64; di += 2) {
    int dr = di + dr2;
    int d = d0 + dr;
    if (d < 416) T[((size_t)b * 416 + d) * 128 + jc] = f2bf(t_sh[dr][jc]);
  }
}

// ---------------- graph MFMA (16-row tiles, quarter-split waves):
// tmpb[b][i][0..415] = bf16( G[b] @ h[b] ). Grid 512 = 64b x 8 tiles, b-chunked.
__global__ __launch_bounds__(256) void k_gmm(const float* __restrict__ G,
    const unsigned short* __restrict__ hT, unsigned short* __restrict__ tmpb) {
  __shared__ unsigned short a_sh[16 * 136];
  const int tid = threadIdx.x;
  const int g = (blockIdx.x & 7) * (gridDim.x >> 3) + (blockIdx.x >> 3);
  const int b = g >> 3;
  const int i0 = (g & 7) * 16;
  for (int idx = tid; idx < 16 * 128; idx += 256) {
    int r = idx >> 7, j = idx & 127;
    int i = i0 + r;
    float v = (i < NODES && j < NODES) ? G[((size_t)b * NODES + i) * NODES + j] : 0.f;
    a_sh[r * 136 + j] = f2bf(v);
  }
  __syncthreads();
  const int lane = tid & 63, w = tid >> 6;
  const int lrow = lane & 15, lk = lane >> 4;
  const int cbeg = w * 7;
  f32x4 acc[7];
#pragma unroll
  for (int c = 0; c < 7; ++c) acc[c] = f32x4{0.f, 0.f, 0.f, 0.f};
  const unsigned short* ap = &a_sh[lrow * 136 + lk * 8];
  const unsigned short* wp = &hT[((size_t)b * 416 + cbeg * 16 + lrow) * 128 + lk * 8];
  for (int ks = 0; ks < 4; ++ks) {
    s16x8 af = *reinterpret_cast<const s16x8*>(ap + ks * 32);
#pragma unroll
    for (int c = 0; c < 7; ++c) {
      s16x8 bf = *reinterpret_cast<const s16x8*>(wp + (size_t)c * 16 * 128 + ks * 32);
      acc[c] = __builtin_amdgcn_mfma_f32_16x16x32_bf16(af, bf, acc[c], 0, 0, 0);
    }
  }
#pragma unroll
  for (int c = 0; c < 7; ++c) {
    int col = (cbeg + c) * 16 + lrow;
    if (col < 416) {
#pragma unroll
      for (int j = 0; j < 4; ++j) {
        int i = i0 + lk * 4 + j;
        if (i < NODES)
          tmpb[((size_t)b * NODES + i) * 416 + col] = f2bf(acc[c][j]);
      }
    }
  }
}

// ---------------- dense LN GEMM (16-row tiles, quarter-split): bf16 A direct.
// Grid 472, XCD row-chunk swizzle. out = LN(relu(A@W+b)+resid)
__global__ __launch_bounds__(256) void k_mgb_ln(
    const unsigned short* __restrict__ A, const unsigned short* __restrict__ Wt,
    const float* __restrict__ bias, const float* __restrict__ resid,
    const float* __restrict__ lns, const float* __restrict__ lnb,
    float* __restrict__ out) {
  __shared__ float ps_sh[16][4][2];
  const int tid = threadIdx.x;
  const int g = (blockIdx.x % 8) * (gridDim.x / 8) + blockIdx.x / 8;
  const size_t row0 = (size_t)g * 16;
  const int lane = tid & 63, w = tid >> 6;
  const int lrow = lane & 15, lk = lane >> 4;
  const int cbeg = w * 7;
  f32x4 acc[7];
#pragma unroll
  for (int c = 0; c < 7; ++c) acc[c] = f32x4{0.f, 0.f, 0.f, 0.f};
  const unsigned short* ap = &A[(row0 + lrow) * 416 + lk * 8];
  const unsigned short* wp = &Wt[((size_t)(cbeg * 16) + lrow) * 416 + lk * 8];
  for (int ks = 0; ks < 13; ++ks) {
    s16x8 af = *reinterpret_cast<const s16x8*>(ap + ks * 32);
#pragma unroll
    for (int c = 0; c < 7; ++c) {
      s16x8 bf = *reinterpret_cast<const s16x8*>(wp + (size_t)c * 16 * 416 + ks * 32);
      acc[c] = __builtin_amdgcn_mfma_f32_16x16x32_bf16(af, bf, acc[c], 0, 0, 0);
    }
  }
  float zs[4], zq[4];
#pragma unroll
  for (int j = 0; j < 4; ++j) { zs[j] = 0.f; zq[j] = 0.f; }
#pragma unroll
  for (int c = 0; c < 7; ++c) {
    int col = (cbeg + c) * 16 + lrow;
    bool cv = col < DD;
    float bv = cv ? bias[col] : 0.f;
#pragma unroll
    for (int j = 0; j < 4; ++j) {
      float z = 0.f;
      if (cv)
        z = fmaxf(acc[c][j] + bv, 0.f) + resid[(row0 + lk * 4 + j) * (size_t)DD + col];
      acc[c][j] = z;
      zs[j] += z;
      zq[j] += z * z;
    }
  }
#pragma unroll
  for (int j = 0; j < 4; ++j) {
    zs[j] += __shfl_xor(zs[j], 1, 64); zq[j] += __shfl_xor(zq[j], 1, 64);
    zs[j] += __shfl_xor(zs[j], 2, 64); zq[j] += __shfl_xor(zq[j], 2, 64);
    zs[j] += __shfl_xor(zs[j], 4, 64); zq[j] += __shfl_xor(zq[j], 4, 64);
    zs[j] += __shfl_xor(zs[j], 8, 64); zq[j] += __shfl_xor(zq[j], 8, 64);
  }
  if (lrow == 0) {
#pragma unroll
    for (int j = 0; j < 4; ++j) {
      ps_sh[lk * 4 + j][w][0] = zs[j];
      ps_sh[lk * 4 + j][w][1] = zq[j];
    }
  }
  __syncthreads();
  float mu[4], rs[4];
#pragma unroll
  for (int j = 0; j < 4; ++j) {
    int la = lk * 4 + j;
    float s = ps_sh[la][0][0] + ps_sh[la][1][0] + ps_sh[la][2][0] + ps_sh[la][3][0];
    float q = ps_sh[la][0][1] + ps_sh[la][1][1] + ps_sh[la][2][1] + ps_sh[la][3][1];
    mu[j] = s * (1.0f / DD);
    rs[j] = 1.0f / sqrtf(q * (1.0f / DD) - mu[j] * mu[j] + 1e-5f);
  }
#pragma unroll
  for (int c = 0; c < 7; ++c) {
    int col = (cbeg + c) * 16 + lrow;
    if (col < DD) {
      float sc = lns[col], bo = lnb[col];
#pragma unroll
      for (int j = 0; j < 4; ++j)
        out[(row0 + lk * 4 + j) * (size_t)DD + col] = (acc[c][j] - mu[j]) * rs[j] * sc + bo;
    }
  }
}

// ---------------- one-shot weight prep (bf16 transposed+padded blobs)
__global__ __launch_bounds__(256) void k_prep_all(const float* __restrict__ gW,
    const float* __restrict__ afW, const float* __restrict__ Kw,
    const float* __restrict__ Qw, const float* __restrict__ icQw,
    const float* __restrict__ icKw, const float* __restrict__ Qb,
    const float* __restrict__ icQb, unsigned short* __restrict__ wbase,
    float* __restrict__ bias3) {
  int idx = blockIdx.x * 256 + threadIdx.x;
  const int SG = 416 * 416;   // 173056
  const int SK = 224 * 416;   // 93184
  if (idx < SG) {             // gW0t
    int n = idx / 416, k = idx - n * 416;
    wbase[idx] = (n < 400 && k < 400) ? f2bf(gW[(size_t)k * 400 + n]) : (unsigned short)0;
    return;
  }
  idx -= SG;
  if (idx < SG) {             // gW1t
    int n = idx / 416, k = idx - n * 416;
    wbase[173056 + idx] = (n < 400 && k < 400) ? f2bf(gW[160000 + (size_t)k * 400 + n]) : (unsigned short)0;
    return;
  }
  idx -= SG;
  if (idx < SG) {             // afWt
    int n = idx / 416, k = idx - n * 416;
    wbase[346112 + idx] = (n < 400 && k < 400) ? f2bf(afW[(size_t)k * 400 + n]) : (unsigned short)0;
    return;
  }
  idx -= SG;
  if (idx < SK) {             // Kwt [224 n][416 k]
    int n = idx / 416, k = idx - n * 416;
    wbase[519168 + idx] = (n < 200 && k < 400) ? f2bf(Kw[(size_t)k * 200 + n]) : (unsigned short)0;
    return;
  }
  idx -= SK;
  if (idx < SK) {             // icKwB [416 d][224 a]
    int d = idx / 224, a = idx - d * 224;
    wbase[612352 + idx] = (d < 400 && a < 200) ? f2bf(icKw[(size_t)d * 200 + a]) : (unsigned short)0;
    return;
  }
  idx -= SK;
  if (idx < SK) {             // icQwB [416 k][224 a]
    int k = idx / 224, a = idx - k * 224;
    wbase[705536 + idx] = (k < 400 && a < 200) ? f2bf(icQw[(size_t)k * 200 + a]) : (unsigned short)0;
    return;
  }
  idx -= SK;
  if (idx < 208 * 416) {      // Wqp rows 0..207 (Q part)
    int n = idx / 416, k = idx - n * 416;
    wbase[798720 + idx] = (n < 200 && k < 400) ? f2bf(Qw[(size_t)k * 200 + n]) : (unsigned short)0;
    return;
  }
  idx -= 208 * 416;
  if (idx < 608) {            // bias3
    float v = 0.f;
    if (idx < 200) v = Qb[idx];
    else if (idx >= 208) {
      const float* kr = icKw + (size_t)(idx - 208) * 200;
      float s = 0.f;
      for (int a = 0; a < 200; ++a) s += icQb[a] * kr[a];
      v = s;
    }
    bias3[idx] = v;
  }
}

// ---------------- M-prep: Wqp[208+d][k] = bf16( sum_a icKw[d,a]*icQw[k,a] ), MFMA
__global__ __launch_bounds__(256) void k_prep_M(const unsigned short* __restrict__ icKwB,
    const unsigned short* __restrict__ icQwB, unsigned short* __restrict__ wqp) {
  const int tid = threadIdx.x;
  const size_t row0 = (size_t)blockIdx.x * 32;
  const int lane = tid & 63, w = tid >> 6;
  const int lrow = lane & 15, lk = lane >> 4;
  const int rg = w & 1, nh = w >> 1;
  const int cbeg = nh * 13;
  f32x4 acc[13];
#pragma unroll
  for (int c = 0; c < 13; ++c) acc[c] = f32x4{0.f, 0.f, 0.f, 0.f};
  const unsigned short* ap = &icKwB[(row0 + rg * 16 + lrow) * 224 + lk * 8];
  const unsigned short* bp = &icQwB[((size_t)(cbeg * 16) + lrow) * 224 + lk * 8];
  for (int ks = 0; ks < 7; ++ks) {
    s16x8 af = *reinterpret_cast<const s16x8*>(ap + ks * 32);
#pragma unroll
    for (int c = 0; c < 13; ++c) {
      s16x8 bf = *reinterpret_cast<const s16x8*>(bp + (size_t)c * 16 * 224 + ks * 32);
      acc[c] = __builtin_amdgcn_mfma_f32_16x16x32_bf16(af, bf, acc[c], 0, 0, 0);
    }
  }
  const int r0 = rg * 16 + lk * 4;
#pragma unroll
  for (int c = 0; c < 13; ++c) {
    int k = (cbeg + c) * 16 + lrow;
#pragma unroll
    for (int j = 0; j < 4; ++j) {
      size_t d = row0 + r0 + j;
      if (d < 400) wqp[(208 + d) * 416 + k] = f2bf(acc[c][j]);
    }
  }
}

// =================== fp32-A MFMA GEMM (v1 decomposition, XCD row-chunk swizzle)
// EPI: 0 plain(colguard), 6 QP dual-output.
template<int KDIM, int KPAD, int NOUT, int EPI>
__global__ __launch_bounds__(256) void k_mg(
    const float* __restrict__ A, const unsigned short* __restrict__ Wt,
    const float* __restrict__ bias, float* __restrict__ out, float* __restrict__ out2) {
  constexpr int APITCH = KPAD + 8;
  constexpr int NF = (NOUT + 15) / 16;
  constexpr int NF0 = (NF + 1) / 2;
  constexpr int KS = KPAD / 32;
  constexpr int E4 = KDIM / 4;
  constexpr int PADN = KPAD - KDIM;
  __shared__ unsigned short a_sh[32 * APITCH];
  const int tid = threadIdx.x;
  const int g = (blockIdx.x % 8) * (gridDim.x / 8) + blockIdx.x / 8;
  const size_t row0 = (size_t)g * 32;
  for (int i = tid; i < 32 * E4; i += 256) {
    int r = i / E4, c4 = i - r * E4;
    const float4 v = *reinterpret_cast<const float4*>(&A[(row0 + r) * (size_t)KDIM + c4 * 4]);
    unsigned int lo = (unsigned int)f2bf(v.x) | ((unsigned int)f2bf(v.y) << 16);
    unsigned int hi = (unsigned int)f2bf(v.z) | ((unsigned int)f2bf(v.w) << 16);
    *reinterpret_cast<uint2*>(&a_sh[r * APITCH + c4 * 4]) = make_uint2(lo, hi);
  }
  for (int i = tid; i < 32 * PADN; i += 256) {
    int r = i / PADN, c = i - r * PADN;
    a_sh[r * APITCH + KDIM + c] = 0;
  }
  __syncthreads();
  const int lane = tid & 63, w = tid >> 6;
  const int lrow = lane & 15, lk = lane >> 4;
  const int rg = w & 1, nh = w >> 1;
  const int cbeg = nh * NF0;
  f32x4 acc[NF0];
#pragma unroll
  for (int c = 0; c < NF0; ++c) acc[c] = f32x4{0.f, 0.f, 0.f, 0.f};
  const unsigned short* ap = &a_sh[(rg * 16 + lrow) * APITCH + lk * 8];
  const unsigned short* wp = &Wt[((size_t)(cbeg * 16) + lrow) * KPAD + lk * 8];
  for (int ks = 0; ks < KS; ++ks) {
    s16x8 af = *reinterpret_cast<const s16x8*>(ap + ks * 32);
#pragma unroll
    for (int c = 0; c < NF0; ++c) {
      s16x8 bf = *reinterpret_cast<const s16x8*>(wp + (size_t)c * 16 * KPAD + ks * 32);
      acc[c] = __builtin_amdgcn_mfma_f32_16x16x32_bf16(af, bf, acc[c], 0, 0, 0);
    }
  }
  const int r0 = rg * 16 + lk * 4;
  if (EPI == 0) {
#pragma unroll
    for (int c = 0; c < NF0; ++c) {
      int col = (cbeg + c) * 16 + lrow;
      if (col < NOUT) {
#pragma unroll
        for (int j = 0; j < 4; ++j)
          out[(row0 + r0 + j) * (size_t)NOUT + col] = acc[c][j];
      }
    }
  } else {  // EPI == 6
#pragma unroll
    for (int c = 0; c < NF0; ++c) {
      int col = (cbeg + c) * 16 + lrow;
      if (col < 200) {
        float bv = bias[col];
#pragma unroll
        for (int j = 0; j < 4; ++j)
          out[(row0 + r0 + j) * (size_t)AA + col] = acc[c][j] + bv;
      } else if (col >= 208 && col < 608) {
        float bv = bias[col];
#pragma unroll
        for (int j = 0; j < 4; ++j)
          out2[(row0 + r0 + j) * (size_t)DD + (col - 208)] = acc[c][j] + bv;
      }
    }
  }
}

// --------- alpha segment-softmax -> P bf16 [b][320 pitch][128]  (b-chunked XCD)
__global__ __launch_bounds__(256) void k_palpha(const float* __restrict__ K,
    const float* __restrict__ Q, const int* __restrict__ cat,
    unsigned short* __restrict__ P) {
  __shared__ float q_sh[AA];
  __shared__ float a_sh[HH];
  __shared__ int c_sh[HH];
  __shared__ float smax[CATN], sden[CATN];
  const int i = blockIdx.x;
  const int xcd = i & 7, s = i >> 3;
  const int b = 8 * xcd + (s >> 4);
  const int n = s & 15;
  const int bn = b * 16 + n;
  const int tid = threadIdx.x;
  if (tid < AA) q_sh[tid] = Q[(size_t)bn * AA + tid];
  if (tid < HH) c_sh[tid] = cat[b * HH + tid];
  __syncthreads();
  if (tid < 2 * HH) {
    int h = tid >> 1, half = tid & 1;
    const float* kp = K + ((size_t)b * HH + h) * AA + half * 100;
    const float* qp = q_sh + half * 100;
    float sv = 0.f;
#pragma unroll 4
    for (int a = 0; a < 100; ++a) sv += kp[a] * qp[a];
    sv += __shfl_xor(sv, 1, 64);
    if (half == 0) a_sh[h] = sv * ATT_INV;
  }
  __syncthreads();
  if (tid < CATN) {
    float m = -3.4e38f;
    for (int h = 0; h < HH; ++h)
      if (c_sh[h] == tid) m = fmaxf(m, a_sh[h]);
    smax[tid] = m;
  }
  __syncthreads();
  if (tid < HH) a_sh[tid] = expf(a_sh[tid] - smax[c_sh[tid]]);
  __syncthreads();
  if (tid < CATN) {
    float dsum = 0.f;
    for (int h = 0; h < HH; ++h)
      if (c_sh[h] == tid) dsum += a_sh[h];
    sden[tid] = dsum;
  }
  __syncthreads();
  if (tid < HH) a_sh[tid] = a_sh[tid] / sden[c_sh[tid]];
  __syncthreads();
  for (int idx = tid; idx < CATN * 128; idx += 256) {
    int c = idx >> 7, h = idx & 127;
    float v = (h < HH && c_sh[h] == c) ? a_sh[h] : 0.f;
    P[((size_t)b * 320 + n * CATN + c) * 128 + h] = f2bf(v);
  }
}

// --------- scatter GEMM (4 waves x 7 frags) -> intraB bf16 [19456][416]; b-chunked
__global__ __launch_bounds__(256) void k_sc(const unsigned short* __restrict__ P,
    const unsigned short* __restrict__ gfT, unsigned short* __restrict__ intraB) {
  const int i = blockIdx.x;
  const int xcd = i & 7, s = i >> 3;
  const int b = 8 * xcd + s / CATN;
  const int t = s % CATN;
  const int tid = threadIdx.x;
  const int lane = tid & 63, w = tid >> 6;
  const int lrow = lane & 15, lk = lane >> 4;
  const int cbeg = w * 7;
  f32x4 acc[7];
#pragma unroll
  for (int c = 0; c < 7; ++c) acc[c] = f32x4{0.f, 0.f, 0.f, 0.f};
  const unsigned short* ap = &P[((size_t)b * 320 + t * 16 + lrow) * 128 + lk * 8];
  const unsigned short* wp = &gfT[((size_t)b * 416 + cbeg * 16 + lrow) * 128 + lk * 8];
  for (int ks = 0; ks < 4; ++ks) {
    s16x8 af = *reinterpret_cast<const s16x8*>(ap + ks * 32);
#pragma unroll
    for (int c = 0; c < 7; ++c) {
      s16x8 bf = *reinterpret_cast<const s16x8*>(wp + (size_t)c * 16 * 128 + ks * 32);
      acc[c] = __builtin_amdgcn_mfma_f32_16x16x32_bf16(af, bf, acc[c], 0, 0, 0);
    }
  }
#pragma unroll
  for (int c = 0; c < 7; ++c) {
    int col = (cbeg + c) * 16 + lrow;
    if (col < 416) {
#pragma unroll
      for (int j = 0; j < 4; ++j)
        intraB[((size_t)b * 304 + t * 16 + lk * 4 + j) * 416 + col] =
            f2bf(col < DD ? acc[c][j] : 0.f);
    }
  }
}

// --------- affine GEMM v5 (16-row tiles, quarter-split): grid 1216.
// bf16 A direct-global. v = relu(A@afW+b)+A ; intra2B = bf16(v) ;
// s_pre[row] = (v.p[row/19])*ATT_INV
__global__ __launch_bounds__(256) void k_afq(
    const unsigned short* __restrict__ A, const unsigned short* __restrict__ Wt,
    const float* __restrict__ bias, const float* __restrict__ p,
    float* __restrict__ s_pre, unsigned short* __restrict__ out2) {
  __shared__ float ps_sh[16][4];
  const int tid = threadIdx.x;
  const int g = (blockIdx.x % 8) * (gridDim.x / 8) + blockIdx.x / 8;
  const size_t row0 = (size_t)g * 16;
  const int lane = tid & 63, w = tid >> 6;
  const int lrow = lane & 15, lk = lane >> 4;
  const int cbeg = w * 7;
  f32x4 acc[7];
#pragma unroll
  for (int c = 0; c < 7; ++c) acc[c] = f32x4{0.f, 0.f, 0.f, 0.f};
  const unsigned short* ap = &A[(row0 + lrow) * 416 + lk * 8];
  const unsigned short* wp = &Wt[((size_t)(cbeg * 16) + lrow) * 416 + lk * 8];
  for (int ks = 0; ks < 13; ++ks) {
    s16x8 af = *reinterpret_cast<const s16x8*>(ap + ks * 32);
#pragma unroll
    for (int c = 0; c < 7; ++c) {
      s16x8 bf = *reinterpret_cast<const s16x8*>(wp + (size_t)c * 16 * 416 + ks * 32);
      acc[c] = __builtin_amdgcn_mfma_f32_16x16x32_bf16(af, bf, acc[c], 0, 0, 0);
    }
  }
  const float* prow[4];
#pragma unroll
  for (int j = 0; j < 4; ++j)
    prow[j] = p + (size_t)((row0 + lk * 4 + j) / CATN) * DD;
  float sp[4] = {0.f, 0.f, 0.f, 0.f};
#pragma unroll
  for (int c = 0; c < 7; ++c) {
    int col = (cbeg + c) * 16 + lrow;
    if (col < DD) {
      float bv = bias[col];
#pragma unroll
      for (int j = 0; j < 4; ++j) {
        size_t ra = row0 + lk * 4 + j;
        float v = fmaxf(acc[c][j] + bv, 0.f) + bf2f(A[ra * 416 + col]);
        out2[ra * 416 + col] = f2bf(v);
        sp[j] += v * prow[j][col];
      }
    }
  }
#pragma unroll
  for (int j = 0; j < 4; ++j) {
    sp[j] += __shfl_xor(sp[j], 1, 64);
    sp[j] += __shfl_xor(sp[j], 2, 64);
    sp[j] += __shfl_xor(sp[j], 4, 64);
    sp[j] += __shfl_xor(sp[j], 8, 64);
  }
  if (lrow == 0) {
#pragma unroll
    for (int j = 0; j < 4; ++j) ps_sh[lk * 4 + j][w] = sp[j];
  }
  __syncthreads();
  if (tid < 16)
    s_pre[row0 + tid] =
        (ps_sh[tid][0] + ps_sh[tid][1] + ps_sh[tid][2] + ps_sh[tid][3]) * ATT_INV;
}

// --------- masked softmax over 19 (s_pre precomputed) ; out = sum_c w*intra2
__global__ __launch_bounds__(256) void k_final(const unsigned short* __restrict__ intra2B,
    const float* __restrict__ s_pre, const int* __restrict__ mask,
    float* __restrict__ out) {
  __shared__ float w_sh[CATN];
  const int i = blockIdx.x;
  const int xcd = i & 7, s = i >> 3;
  const int b = 8 * xcd + (s >> 4);
  const int n = s & 15;
  const int bn = b * 16 + n;
  const int tid = threadIdx.x;
  if (tid == 0) {
    float sv[CATN];
    float mx = -3.4e38f;
#pragma unroll
    for (int c = 0; c < CATN; ++c) {
      bool mk = (c == CATN - 1) || (mask[b * CATN + c] != 0);
      float sc = mk ? s_pre[bn * CATN + c] : -3.4e38f;
      sv[c] = sc;
      mx = fmaxf(mx, sc);
    }
    float den = 0.f;
#pragma unroll
    for (int c = 0; c < CATN; ++c) {
      float e = (sv[c] <= -3.3e38f) ? 0.f : expf(sv[c] - mx);
      w_sh[c] = e;
      den += e;
    }
    float inv = 1.0f / den;
#pragma unroll
    for (int c = 0; c < CATN; ++c) w_sh[c] *= inv;
  }
  __syncthreads();
  const unsigned short* ib = intra2B + (size_t)bn * CATN * 416;
  for (int d = tid; d < DD; d += 256) {
    float o = 0.f;
#pragma unroll
    for (int c = 0; c < CATN; ++c) o += w_sh[c] * bf2f(ib[c * 416 + d]);
    out[(size_t)bn * DD + d] = o;
  }
}

// ============================================================================
extern "C" void kernel_launch(void* const* d_in, const int* in_sizes, int n_in,
                              void* d_out, int out_size, void* d_ws, size_t ws_size,
                              hipStream_t stream) {
  const float* hist  = (const float*)d_in[0];
  const float* cand  = (const float*)d_in[1];
  const float* G     = (const float*)d_in[2];
  const int*   cmask = (const int*)d_in[3];
  const int*   cidx  = (const int*)d_in[4];
  const float* proxy = (const float*)d_in[5];
  const float* gW    = (const float*)d_in[6];
  const float* gb    = (const float*)d_in[7];
  const float* lns   = (const float*)d_in[8];
  const float* lnb   = (const float*)d_in[9];
  const float* Kw    = (const float*)d_in[10];
  const float* Qw    = (const float*)d_in[11];
  const float* Qbb   = (const float*)d_in[12];
  const float* afW   = (const float*)d_in[13];
  const float* afb   = (const float*)d_in[14];
  const float* icKw  = (const float*)d_in[15];
  const float* icQw  = (const float*)d_in[16];
  const float* icQb  = (const float*)d_in[17];
  float* out = (float*)d_out;
  float* ws  = (float*)d_ws;

  // ---- workspace layout (float offsets) ---- (same as round 10)
  float* he    = ws;
  float* s1    = ws + 3020800;
  float* s2f   = ws + 6041600;
  unsigned short* tmpb   = (unsigned short*)(ws + 6041600);
  unsigned short* TB     = (unsigned short*)(ws + 9062400);
  unsigned short* intraB = (unsigned short*)(ws + 10766336);
  unsigned short* intra2B= (unsigned short*)(ws + 14813184);
  unsigned short* wbase  = (unsigned short*)(ws + 18860032);
  float* bias3 = ws + 19385856;
  unsigned short* Pbuf = (unsigned short*)ws;
  float* qbuf  = ws + 1310720;                  // [1024][200]
  float* pbuf  = ws + 1515520;                  // [1024][400]
  float* s_pre = ws + 1925120;                  // [19456]
  float* Kbuf  = s1;
  unsigned short* gW0t  = wbase;
  unsigned short* gW1t  = wbase + 173056;
  unsigned short* afWt  = wbase + 346112;
  unsigned short* Kwt   = wbase + 519168;       // [224][416]
  unsigned short* icKwB = wbase + 612352;       // [416][224]
  unsigned short* icQwB = wbase + 705536;       // [416][224]
  unsigned short* Wqp   = wbase + 798720;       // [608][416]

  // 0. weight prep + fused icQ->p matrix
  k_prep_all<<<3461, 256, 0, stream>>>(gW, afW, Kw, Qw, icQw, icKw, Qbb, icQb, wbase, bias3);
  k_prep_M<<<13, 256, 0, stream>>>(icKwB, icQwB, Wqp);
  // 1. fused concat + transpose: he + hT
  k_toT_he<<<448, 256, 0, stream>>>(hist, proxy, he, TB);
  // 2-3. GCN layer 0 (16-row tiles)
  k_gmm<<<512, 256, 0, stream>>>(G, TB, tmpb);
  k_mgb_ln<<<BN / 16, 256, 0, stream>>>(tmpb, gW0t, gb, he, lns, lnb, s1);
  // 4-6. GCN layer 1 (in-place s1)
  k_toT<NODES><<<448, 256, 0, stream>>>(s1, TB);
  k_gmm<<<512, 256, 0, stream>>>(G, TB, tmpb);
  k_mgb_ln<<<BN / 16, 256, 0, stream>>>(tmpb, gW1t, gb + DD, s1, lns + DD, lnb + DD, s1);
  // 7. fused gf = (h2+he)[:, :HH] + transpose: gf + gfT
  k_toT_gf<<<448, 256, 0, stream>>>(s1, he, s2f, TB);
  // 8. K = gf @ Kw -> Kbuf (grid 200 %8==0)
  k_mg<400, 416, 200, 0><<<BH / 32, 256, 0, stream>>>(s2f, Kwt, nullptr, Kbuf, nullptr);
  // 9. fused Q-proj + p-proj (grid 32 %8==0)
  k_mg<400, 416, 608, 6><<<BB * NN / 32, 256, 0, stream>>>(cand, Wqp, bias3, qbuf, pbuf);
  // 10. alpha -> P (b-chunked XCD)
  k_palpha<<<BB * NN, 256, 0, stream>>>(Kbuf, qbuf, cidx, Pbuf);
  // 11. intra = P @ gf -> intraB bf16 (4-wave blocks, b-chunked XCD)
  k_sc<<<BB * CATN, 256, 0, stream>>>(Pbuf, TB, intraB);
  // 12. affine v5 (16-row, grid 1216) + fused s-dot -> intra2B, s_pre
  k_afq<<<BB * NN * CATN / 16, 256, 0, stream>>>(intraB, afWt, afb, pbuf, s_pre, intra2B);
  // 13. final softmax + weighted sum (b-chunked XCD)
  k_final<<<BB * NN, 256, 0, stream>>>(intra2B, s_pre, cmask, out);
}

// Round 16
// 289.990 us; speedup vs baseline: 1.5634x; 1.0742x over previous
//
#include <hip/hip_runtime.h>
#include <hip/hip_bf16.h>
#include <math.h>

#define BB 64
#define NN 16
#define HH 100
#define DD 400
#define AA 200
#define CATN 19
#define NODES 118            // HH + CATN-1
#define BN (BB*NODES)        // 7552
#define BH (BB*HH)           // 6400
#define ATT_INV 0.07071067811865475f   // 1/sqrt(200)

typedef __attribute__((ext_vector_type(4))) float f32x4;
typedef __attribute__((ext_vector_type(8))) short s16x8;

__device__ __forceinline__ unsigned short f2bf(float f) {
  union { float f; unsigned int u; } v; v.f = f;
  unsigned int r = v.u + 0x7FFFu + ((v.u >> 16) & 1u);
  return (unsigned short)(r >> 16);
}
__device__ __forceinline__ float bf2f(unsigned short u) {
  union { unsigned int i; float f; } v; v.i = ((unsigned int)u) << 16; return v.f;
}

// ---------------- fused concat + transpose: he fp32 + hT bf16 [b][416][128]
__global__ __launch_bounds__(256) void k_toT_he(const float* __restrict__ hist,
    const float* __restrict__ proxy, float* __restrict__ he,
    unsigned short* __restrict__ T) {
  __shared__ float t_sh[64][129];
  const int b = blockIdx.x / 7, dt = blockIdx.x % 7;
  const int d0 = dt * 64;
  const int tid = threadIdx.x;
  const int dc = tid & 63, jr = tid >> 6;
  for (int j0 = 0; j0 < 128; j0 += 4) {
    int j = j0 + jr, d = d0 + dc;
    float v = 0.f;
    if (j < NODES && d < DD) {
      v = (j < HH) ? hist[((size_t)b * HH + j) * DD + d]
                   : proxy[(size_t)(j - HH) * DD + d];
      he[((size_t)b * NODES + j) * DD + d] = v;
    }
    t_sh[dc][j] = v;
  }
  __syncthreads();
  const int jc = tid & 127, dr2 = tid >> 7;
  for (int di = 0; di < 64; di += 2) {
    int dr = di + dr2;
    int d = d0 + dr;
    if (d < 416) T[((size_t)b * 416 + d) * 128 + jc] = f2bf(t_sh[dr][jc]);
  }
}

// ---------------- graph MFMA (16-row tiles, quarter-split waves):
// tmpb[b][i][0..415] = bf16( G[b] @ h[b] ). Grid 512 = 64b x 8 tiles, b-chunked.
__global__ __launch_bounds__(256) void k_gmm(const float* __restrict__ G,
    const unsigned short* __restrict__ hT, unsigned short* __restrict__ tmpb) {
  __shared__ unsigned short a_sh[16 * 136];
  const int tid = threadIdx.x;
  const int g = (blockIdx.x & 7) * (gridDim.x >> 3) + (blockIdx.x >> 3);
  const int b = g >> 3;
  const int i0 = (g & 7) * 16;
  for (int idx = tid; idx < 16 * 128; idx += 256) {
    int r = idx >> 7, j = idx & 127;
    int i = i0 + r;
    float v = (i < NODES && j < NODES) ? G[((size_t)b * NODES + i) * NODES + j] : 0.f;
    a_sh[r * 136 + j] = f2bf(v);
  }
  __syncthreads();
  const int lane = tid & 63, w = tid >> 6;
  const int lrow = lane & 15, lk = lane >> 4;
  const int cbeg = w * 7;
  f32x4 acc[7];
#pragma unroll
  for (int c = 0; c < 7; ++c) acc[c] = f32x4{0.f, 0.f, 0.f, 0.f};
  const unsigned short* ap = &a_sh[lrow * 136 + lk * 8];
  const unsigned short* wp = &hT[((size_t)b * 416 + cbeg * 16 + lrow) * 128 + lk * 8];
  for (int ks = 0; ks < 4; ++ks) {
    s16x8 af = *reinterpret_cast<const s16x8*>(ap + ks * 32);
#pragma unroll
    for (int c = 0; c < 7; ++c) {
      s16x8 bf = *reinterpret_cast<const s16x8*>(wp + (size_t)c * 16 * 128 + ks * 32);
      acc[c] = __builtin_amdgcn_mfma_f32_16x16x32_bf16(af, bf, acc[c], 0, 0, 0);
    }
  }
#pragma unroll
  for (int c = 0; c < 7; ++c) {
    int col = (cbeg + c) * 16 + lrow;
    if (col < 416) {
#pragma unroll
      for (int j = 0; j < 4; ++j) {
        int i = i0 + lk * 4 + j;
        if (i < NODES)
          tmpb[((size_t)b * NODES + i) * 416 + col] = f2bf(acc[c][j]);
      }
    }
  }
}

// ---------------- dense LN GEMM (16-row tiles, quarter-split) + fused transpose.
// MODE 0: out = LN(...) fp32 [BN][400] ; T[b][col][i] = bf16(out)        (layer 0)
// MODE 1: g = LN(...) + he ; gf[b*100+i][col] = g (i<100) ;
//         T[b][col][i] = bf16(g) for i<100, 0 for 100<=i<118           (layer 1)
template<int MODE>
__global__ __launch_bounds__(256) void k_mgb_ln(
    const unsigned short* __restrict__ A, const unsigned short* __restrict__ Wt,
    const float* __restrict__ bias, const float* __restrict__ resid,
    const float* __restrict__ lns, const float* __restrict__ lnb,
    float* __restrict__ out, unsigned short* __restrict__ T,
    const float* __restrict__ he) {
  __shared__ float ps_sh[16][4][2];
  const int tid = threadIdx.x;
  const int g = (blockIdx.x % 8) * (gridDim.x / 8) + blockIdx.x / 8;
  const size_t row0 = (size_t)g * 16;
  const int lane = tid & 63, w = tid >> 6;
  const int lrow = lane & 15, lk = lane >> 4;
  const int cbeg = w * 7;
  f32x4 acc[7];
#pragma unroll
  for (int c = 0; c < 7; ++c) acc[c] = f32x4{0.f, 0.f, 0.f, 0.f};
  const unsigned short* ap = &A[(row0 + lrow) * 416 + lk * 8];
  const unsigned short* wp = &Wt[((size_t)(cbeg * 16) + lrow) * 416 + lk * 8];
  for (int ks = 0; ks < 13; ++ks) {
    s16x8 af = *reinterpret_cast<const s16x8*>(ap + ks * 32);
#pragma unroll
    for (int c = 0; c < 7; ++c) {
      s16x8 bf = *reinterpret_cast<const s16x8*>(wp + (size_t)c * 16 * 416 + ks * 32);
      acc[c] = __builtin_amdgcn_mfma_f32_16x16x32_bf16(af, bf, acc[c], 0, 0, 0);
    }
  }
  float zs[4], zq[4];
#pragma unroll
  for (int j = 0; j < 4; ++j) { zs[j] = 0.f; zq[j] = 0.f; }
#pragma unroll
  for (int c = 0; c < 7; ++c) {
    int col = (cbeg + c) * 16 + lrow;
    bool cv = col < DD;
    float bv = cv ? bias[col] : 0.f;
#pragma unroll
    for (int j = 0; j < 4; ++j) {
      float z = 0.f;
      if (cv)
        z = fmaxf(acc[c][j] + bv, 0.f) + resid[(row0 + lk * 4 + j) * (size_t)DD + col];
      acc[c][j] = z;
      zs[j] += z;
      zq[j] += z * z;
    }
  }
#pragma unroll
  for (int j = 0; j < 4; ++j) {
    zs[j] += __shfl_xor(zs[j], 1, 64); zq[j] += __shfl_xor(zq[j], 1, 64);
    zs[j] += __shfl_xor(zs[j], 2, 64); zq[j] += __shfl_xor(zq[j], 2, 64);
    zs[j] += __shfl_xor(zs[j], 4, 64); zq[j] += __shfl_xor(zq[j], 4, 64);
    zs[j] += __shfl_xor(zs[j], 8, 64); zq[j] += __shfl_xor(zq[j], 8, 64);
  }
  if (lrow == 0) {
#pragma unroll
    for (int j = 0; j < 4; ++j) {
      ps_sh[lk * 4 + j][w][0] = zs[j];
      ps_sh[lk * 4 + j][w][1] = zq[j];
    }
  }
  __syncthreads();
  float mu[4], rs[4];
#pragma unroll
  for (int j = 0; j < 4; ++j) {
    int la = lk * 4 + j;
    float s = ps_sh[la][0][0] + ps_sh[la][1][0] + ps_sh[la][2][0] + ps_sh[la][3][0];
    float q = ps_sh[la][0][1] + ps_sh[la][1][1] + ps_sh[la][2][1] + ps_sh[la][3][1];
    mu[j] = s * (1.0f / DD);
    rs[j] = 1.0f / sqrtf(q * (1.0f / DD) - mu[j] * mu[j] + 1e-5f);
  }
#pragma unroll
  for (int c = 0; c < 7; ++c) {
    int col = (cbeg + c) * 16 + lrow;
    if (col < DD) {
      float sc = lns[col], bo = lnb[col];
#pragma unroll
      for (int j = 0; j < 4; ++j) {
        size_t row = row0 + lk * 4 + j;
        int b = (int)(row / NODES);
        int i = (int)(row - (size_t)b * NODES);
        float v = (acc[c][j] - mu[j]) * rs[j] * sc + bo;
        if (MODE == 0) {
          out[row * (size_t)DD + col] = v;
          T[((size_t)b * 416 + col) * 128 + i] = f2bf(v);
        } else {
          if (i < HH) {
            float gg = v + he[row * (size_t)DD + col];
            out[((size_t)b * HH + i) * (size_t)DD + col] = gg;
            T[((size_t)b * 416 + col) * 128 + i] = f2bf(gg);
          } else {
            T[((size_t)b * 416 + col) * 128 + i] = 0;
          }
        }
      }
    }
  }
}

// ---------------- one-shot weight prep (bf16 transposed+padded blobs)
// gW0t@0 [416][416], gW1t@173056, afWt@346112, Kwt@519168 [224][416],
// icKwB@612352 [416][224], icQwB@705536 [416][224], Wqp@798720 [640][416]
// (rows 0..207 Q-part, 208..607 by k_prep_M, 608..639 zeroed here)
// bias3 float[608]: 0..199 Qb ; 208..607 pb[d] = icQb . icKw[d,:]
__global__ __launch_bounds__(256) void k_prep_all(const float* __restrict__ gW,
    const float* __restrict__ afW, const float* __restrict__ Kw,
    const float* __restrict__ Qw, const float* __restrict__ icQw,
    const float* __restrict__ icKw, const float* __restrict__ Qb,
    const float* __restrict__ icQb, unsigned short* __restrict__ wbase,
    float* __restrict__ bias3) {
  int idx = blockIdx.x * 256 + threadIdx.x;
  const int SG = 416 * 416;   // 173056
  const int SK = 224 * 416;   // 93184
  if (idx < SG) {             // gW0t
    int n = idx / 416, k = idx - n * 416;
    wbase[idx] = (n < 400 && k < 400) ? f2bf(gW[(size_t)k * 400 + n]) : (unsigned short)0;
    return;
  }
  idx -= SG;
  if (idx < SG) {             // gW1t
    int n = idx / 416, k = idx - n * 416;
    wbase[173056 + idx] = (n < 400 && k < 400) ? f2bf(gW[160000 + (size_t)k * 400 + n]) : (unsigned short)0;
    return;
  }
  idx -= SG;
  if (idx < SG) {             // afWt
    int n = idx / 416, k = idx - n * 416;
    wbase[346112 + idx] = (n < 400 && k < 400) ? f2bf(afW[(size_t)k * 400 + n]) : (unsigned short)0;
    return;
  }
  idx -= SG;
  if (idx < SK) {             // Kwt [224 n][416 k]
    int n = idx / 416, k = idx - n * 416;
    wbase[519168 + idx] = (n < 200 && k < 400) ? f2bf(Kw[(size_t)k * 200 + n]) : (unsigned short)0;
    return;
  }
  idx -= SK;
  if (idx < SK) {             // icKwB [416 d][224 a]
    int d = idx / 224, a = idx - d * 224;
    wbase[612352 + idx] = (d < 400 && a < 200) ? f2bf(icKw[(size_t)d * 200 + a]) : (unsigned short)0;
    return;
  }
  idx -= SK;
  if (idx < SK) {             // icQwB [416 k][224 a]
    int k = idx / 224, a = idx - k * 224;
    wbase[705536 + idx] = (k < 400 && a < 200) ? f2bf(icQw[(size_t)k * 200 + a]) : (unsigned short)0;
    return;
  }
  idx -= SK;
  if (idx < 208 * 416) {      // Wqp rows 0..207 (Q part)
    int n = idx / 416, k = idx - n * 416;
    wbase[798720 + idx] = (n < 200 && k < 400) ? f2bf(Qw[(size_t)k * 200 + n]) : (unsigned short)0;
    return;
  }
  idx -= 208 * 416;
  if (idx < 32 * 416) {       // Wqp rows 608..639 zero pad
    wbase[798720 + 608 * 416 + idx] = 0;
    return;
  }
  idx -= 32 * 416;
  if (idx < 608) {            // bias3
    float v = 0.f;
    if (idx < 200) v = Qb[idx];
    else if (idx >= 208) {
      const float* kr = icKw + (size_t)(idx - 208) * 200;
      float s = 0.f;
      for (int a = 0; a < 200; ++a) s += icQb[a] * kr[a];
      v = s;
    }
    bias3[idx] = v;
  }
}

// ---------------- M-prep: Wqp[208+d][k] = bf16( sum_a icKw[d,a]*icQw[k,a] ), MFMA
__global__ __launch_bounds__(256) void k_prep_M(const unsigned short* __restrict__ icKwB,
    const unsigned short* __restrict__ icQwB, unsigned short* __restrict__ wqp) {
  const int tid = threadIdx.x;
  const size_t row0 = (size_t)blockIdx.x * 32;
  const int lane = tid & 63, w = tid >> 6;
  const int lrow = lane & 15, lk = lane >> 4;
  const int rg = w & 1, nh = w >> 1;
  const int cbeg = nh * 13;
  f32x4 acc[13];
#pragma unroll
  for (int c = 0; c < 13; ++c) acc[c] = f32x4{0.f, 0.f, 0.f, 0.f};
  const unsigned short* ap = &icKwB[(row0 + rg * 16 + lrow) * 224 + lk * 8];
  const unsigned short* bp = &icQwB[((size_t)(cbeg * 16) + lrow) * 224 + lk * 8];
  for (int ks = 0; ks < 7; ++ks) {
    s16x8 af = *reinterpret_cast<const s16x8*>(ap + ks * 32);
#pragma unroll
    for (int c = 0; c < 13; ++c) {
      s16x8 bf = *reinterpret_cast<const s16x8*>(bp + (size_t)c * 16 * 224 + ks * 32);
      acc[c] = __builtin_amdgcn_mfma_f32_16x16x32_bf16(af, bf, acc[c], 0, 0, 0);
    }
  }
  const int r0 = rg * 16 + lk * 4;
#pragma unroll
  for (int c = 0; c < 13; ++c) {
    int k = (cbeg + c) * 16 + lrow;
#pragma unroll
    for (int j = 0; j < 4; ++j) {
      size_t d = row0 + r0 + j;
      if (d < 400) wqp[(208 + d) * 416 + k] = f2bf(acc[c][j]);
    }
  }
}

// =================== fp32-A MFMA GEMM, 16-row tiles, 4 waves x NFW frags.
// XCD row-chunk swizzle (gridDim.x %8==0). Overrun B-frag reads must land in
// allocated memory (caller guarantees). EPI: 0 plain(colguard), 6 QP dual-out.
template<int KDIM, int KPAD, int NOUT, int NFW, int EPI>
__global__ __launch_bounds__(256) void k_mg16(
    const float* __restrict__ A, const unsigned short* __restrict__ Wt,
    const float* __restrict__ bias, float* __restrict__ out, float* __restrict__ out2) {
  constexpr int APITCH = KPAD + 8;
  constexpr int E4 = KDIM / 4;
  constexpr int PADN = KPAD - KDIM;
  constexpr int KS = KPAD / 32;
  __shared__ unsigned short a_sh[16 * APITCH];
  const int tid = threadIdx.x;
  const int g = (blockIdx.x % 8) * (gridDim.x / 8) + blockIdx.x / 8;
  const size_t row0 = (size_t)g * 16;
  for (int i = tid; i < 16 * E4; i += 256) {
    int r = i / E4, c4 = i - r * E4;
    const float4 v = *reinterpret_cast<const float4*>(&A[(row0 + r) * (size_t)KDIM + c4 * 4]);
    unsigned int lo = (unsigned int)f2bf(v.x) | ((unsigned int)f2bf(v.y) << 16);
    unsigned int hi = (unsigned int)f2bf(v.z) | ((unsigned int)f2bf(v.w) << 16);
    *reinterpret_cast<uint2*>(&a_sh[r * APITCH + c4 * 4]) = make_uint2(lo, hi);
  }
  for (int i = tid; i < 16 * PADN; i += 256) {
    int r = i / PADN, c = i - r * PADN;
    a_sh[r * APITCH + KDIM + c] = 0;
  }
  __syncthreads();
  const int lane = tid & 63, w = tid >> 6;
  const int lrow = lane & 15, lk = lane >> 4;
  const int cbeg = w * NFW;
  f32x4 acc[NFW];
#pragma unroll
  for (int c = 0; c < NFW; ++c) acc[c] = f32x4{0.f, 0.f, 0.f, 0.f};
  const unsigned short* ap = &a_sh[lrow * APITCH + lk * 8];
  const unsigned short* wp = &Wt[((size_t)(cbeg * 16) + lrow) * KPAD + lk * 8];
  for (int ks = 0; ks < KS; ++ks) {
    s16x8 af = *reinterpret_cast<const s16x8*>(ap + ks * 32);
#pragma unroll
    for (int c = 0; c < NFW; ++c) {
      s16x8 bf = *reinterpret_cast<const s16x8*>(wp + (size_t)c * 16 * KPAD + ks * 32);
      acc[c] = __builtin_amdgcn_mfma_f32_16x16x32_bf16(af, bf, acc[c], 0, 0, 0);
    }
  }
  if (EPI == 0) {
#pragma unroll
    for (int c = 0; c < NFW; ++c) {
      int col = (cbeg + c) * 16 + lrow;
      if (col < NOUT) {
#pragma unroll
        for (int j = 0; j < 4; ++j)
          out[(row0 + lk * 4 + j) * (size_t)NOUT + col] = acc[c][j];
      }
    }
  } else {  // EPI == 6
#pragma unroll
    for (int c = 0; c < NFW; ++c) {
      int col = (cbeg + c) * 16 + lrow;
      if (col < 200) {
        float bv = bias[col];
#pragma unroll
        for (int j = 0; j < 4; ++j)
          out[(row0 + lk * 4 + j) * (size_t)AA + col] = acc[c][j] + bv;
      } else if (col >= 208 && col < 608) {
        float bv = bias[col];
#pragma unroll
        for (int j = 0; j < 4; ++j)
          out2[(row0 + lk * 4 + j) * (size_t)DD + (col - 208)] = acc[c][j] + bv;
      }
    }
  }
}

// --------- alpha segment-softmax -> P bf16 [b][320 pitch][128]  (b-chunked XCD)
__global__ __launch_bounds__(256) void k_palpha(const float* __restrict__ K,
    const float* __restrict__ Q, const int* __restrict__ cat,
    unsigned short* __restrict__ P) {
  __shared__ float q_sh[AA];
  __shared__ float a_sh[HH];
  __shared__ int c_sh[HH];
  __shared__ float smax[CATN], sden[CATN];
  const int i = blockIdx.x;
  const int xcd = i & 7, s = i >> 3;
  const int b = 8 * xcd + (s >> 4);
  const int n = s & 15;
  const int bn = b * 16 + n;
  const int tid = threadIdx.x;
  if (tid < AA) q_sh[tid] = Q[(size_t)bn * AA + tid];
  if (tid < HH) c_sh[tid] = cat[b * HH + tid];
  __syncthreads();
  if (tid < 2 * HH) {
    int h = tid >> 1, half = tid & 1;
    const float* kp = K + ((size_t)b * HH + h) * AA + half * 100;
    const float* qp = q_sh + half * 100;
    float sv = 0.f;
#pragma unroll 4
    for (int a = 0; a < 100; ++a) sv += kp[a] * qp[a];
    sv += __shfl_xor(sv, 1, 64);
    if (half == 0) a_sh[h] = sv * ATT_INV;
  }
  __syncthreads();
  if (tid < CATN) {
    float m = -3.4e38f;
    for (int h = 0; h < HH; ++h)
      if (c_sh[h] == tid) m = fmaxf(m, a_sh[h]);
    smax[tid] = m;
  }
  __syncthreads();
  if (tid < HH) a_sh[tid] = expf(a_sh[tid] - smax[c_sh[tid]]);
  __syncthreads();
  if (tid < CATN) {
    float dsum = 0.f;
    for (int h = 0; h < HH; ++h)
      if (c_sh[h] == tid) dsum += a_sh[h];
    sden[tid] = dsum;
  }
  __syncthreads();
  if (tid < HH) a_sh[tid] = a_sh[tid] / sden[c_sh[tid]];
  __syncthreads();
  for (int idx = tid; idx < CATN * 128; idx += 256) {
    int c = idx >> 7, h = idx & 127;
    float v = (h < HH && c_sh[h] == c) ? a_sh[h] : 0.f;
    P[((size_t)b * 320 + n * CATN + c) * 128 + h] = f2bf(v);
  }
}

// --------- scatter GEMM (4 waves x 7 frags) -> intraB bf16 [19456][416]; b-chunked
__global__ __launch_bounds__(256) void k_sc(const unsigned short* __restrict__ P,
    const unsigned short* __restrict__ gfT, unsigned short* __restrict__ intraB) {
  const int i = blockIdx.x;
  const int xcd = i & 7, s = i >> 3;
  const int b = 8 * xcd + s / CATN;
  const int t = s % CATN;
  const int tid = threadIdx.x;
  const int lane = tid & 63, w = tid >> 6;
  const int lrow = lane & 15, lk = lane >> 4;
  const int cbeg = w * 7;
  f32x4 acc[7];
#pragma unroll
  for (int c = 0; c < 7; ++c) acc[c] = f32x4{0.f, 0.f, 0.f, 0.f};
  const unsigned short* ap = &P[((size_t)b * 320 + t * 16 + lrow) * 128 + lk * 8];
  const unsigned short* wp = &gfT[((size_t)b * 416 + cbeg * 16 + lrow) * 128 + lk * 8];
  for (int ks = 0; ks < 4; ++ks) {
    s16x8 af = *reinterpret_cast<const s16x8*>(ap + ks * 32);
#pragma unroll
    for (int c = 0; c < 7; ++c) {
      s16x8 bf = *reinterpret_cast<const s16x8*>(wp + (size_t)c * 16 * 128 + ks * 32);
      acc[c] = __builtin_amdgcn_mfma_f32_16x16x32_bf16(af, bf, acc[c], 0, 0, 0);
    }
  }
#pragma unroll
  for (int c = 0; c < 7; ++c) {
    int col = (cbeg + c) * 16 + lrow;
    if (col < 416) {
#pragma unroll
      for (int j = 0; j < 4; ++j)
        intraB[((size_t)b * 304 + t * 16 + lk * 4 + j) * 416 + col] =
            f2bf(col < DD ? acc[c][j] : 0.f);
    }
  }
}

// --------- affine GEMM v5 (16-row tiles, quarter-split): grid 1216.
// bf16 A direct-global. v = relu(A@afW+b)+A ; intra2B = bf16(v) ;
// s_pre[row] = (v.p[row/19])*ATT_INV
__global__ __launch_bounds__(256) void k_afq(
    const unsigned short* __restrict__ A, const unsigned short* __restrict__ Wt,
    const float* __restrict__ bias, const float* __restrict__ p,
    float* __restrict__ s_pre, unsigned short* __restrict__ out2) {
  __shared__ float ps_sh[16][4];
  const int tid = threadIdx.x;
  const int g = (blockIdx.x % 8) * (gridDim.x / 8) + blockIdx.x / 8;
  const size_t row0 = (size_t)g * 16;
  const int lane = tid & 63, w = tid >> 6;
  const int lrow = lane & 15, lk = lane >> 4;
  const int cbeg = w * 7;
  f32x4 acc[7];
#pragma unroll
  for (int c = 0; c < 7; ++c) acc[c] = f32x4{0.f, 0.f, 0.f, 0.f};
  const unsigned short* ap = &A[(row0 + lrow) * 416 + lk * 8];
  const unsigned short* wp = &Wt[((size_t)(cbeg * 16) + lrow) * 416 + lk * 8];
  for (int ks = 0; ks < 13; ++ks) {
    s16x8 af = *reinterpret_cast<const s16x8*>(ap + ks * 32);
#pragma unroll
    for (int c = 0; c < 7; ++c) {
      s16x8 bf = *reinterpret_cast<const s16x8*>(wp + (size_t)c * 16 * 416 + ks * 32);
      acc[c] = __builtin_amdgcn_mfma_f32_16x16x32_bf16(af, bf, acc[c], 0, 0, 0);
    }
  }
  const float* prow[4];
#pragma unroll
  for (int j = 0; j < 4; ++j)
    prow[j] = p + (size_t)((row0 + lk * 4 + j) / CATN) * DD;
  float sp[4] = {0.f, 0.f, 0.f, 0.f};
#pragma unroll
  for (int c = 0; c < 7; ++c) {
    int col = (cbeg + c) * 16 + lrow;
    if (col < DD) {
      float bv = bias[col];
#pragma unroll
      for (int j = 0; j < 4; ++j) {
        size_t ra = row0 + lk * 4 + j;
        float v = fmaxf(acc[c][j] + bv, 0.f) + bf2f(A[ra * 416 + col]);
        out2[ra * 416 + col] = f2bf(v);
        sp[j] += v * prow[j][col];
      }
    }
  }
#pragma unroll
  for (int j = 0; j < 4; ++j) {
    sp[j] += __shfl_xor(sp[j], 1, 64);
    sp[j] += __shfl_xor(sp[j], 2, 64);
    sp[j] += __shfl_xor(sp[j], 4, 64);
    sp[j] += __shfl_xor(sp[j], 8, 64);
  }
  if (lrow == 0) {
#pragma unroll
    for (int j = 0; j < 4; ++j) ps_sh[lk * 4 + j][w] = sp[j];
  }
  __syncthreads();
  if (tid < 16)
    s_pre[row0 + tid] =
        (ps_sh[tid][0] + ps_sh[tid][1] + ps_sh[tid][2] + ps_sh[tid][3]) * ATT_INV;
}

// --------- masked softmax over 19 (s_pre precomputed) ; out = sum_c w*intra2
__global__ __launch_bounds__(256) void k_final(const unsigned short* __restrict__ intra2B,
    const float* __restrict__ s_pre, const int* __restrict__ mask,
    float* __restrict__ out) {
  __shared__ float w_sh[CATN];
  const int i = blockIdx.x;
  const int xcd = i & 7, s = i >> 3;
  const int b = 8 * xcd + (s >> 4);
  const int n = s & 15;
  const int bn = b * 16 + n;
  const int tid = threadIdx.x;
  if (tid == 0) {
    float sv[CATN];
    float mx = -3.4e38f;
#pragma unroll
    for (int c = 0; c < CATN; ++c) {
      bool mk = (c == CATN - 1) || (mask[b * CATN + c] != 0);
      float sc = mk ? s_pre[bn * CATN + c] : -3.4e38f;
      sv[c] = sc;
      mx = fmaxf(mx, sc);
    }
    float den = 0.f;
#pragma unroll
    for (int c = 0; c < CATN; ++c) {
      float e = (sv[c] <= -3.3e38f) ? 0.f : expf(sv[c] - mx);
      w_sh[c] = e;
      den += e;
    }
    float inv = 1.0f / den;
#pragma unroll
    for (int c = 0; c < CATN; ++c) w_sh[c] *= inv;
  }
  __syncthreads();
  const unsigned short* ib = intra2B + (size_t)bn * CATN * 416;
  for (int d = tid; d < DD; d += 256) {
    float o = 0.f;
#pragma unroll
    for (int c = 0; c < CATN; ++c) o += w_sh[c] * bf2f(ib[c * 416 + d]);
    out[(size_t)bn * DD + d] = o;
  }
}

// ============================================================================
extern "C" void kernel_launch(void* const* d_in, const int* in_sizes, int n_in,
                              void* d_out, int out_size, void* d_ws, size_t ws_size,
                              hipStream_t stream) {
  const float* hist  = (const float*)d_in[0];
  const float* cand  = (const float*)d_in[1];
  const float* G     = (const float*)d_in[2];
  const int*   cmask = (const int*)d_in[3];
  const int*   cidx  = (const int*)d_in[4];
  const float* proxy = (const float*)d_in[5];
  const float* gW    = (const float*)d_in[6];
  const float* gb    = (const float*)d_in[7];
  const float* lns   = (const float*)d_in[8];
  const float* lnb   = (const float*)d_in[9];
  const float* Kw    = (const float*)d_in[10];
  const float* Qw    = (const float*)d_in[11];
  const float* Qbb   = (const float*)d_in[12];
  const float* afW   = (const float*)d_in[13];
  const float* afb   = (const float*)d_in[14];
  const float* icKw  = (const float*)d_in[15];
  const float* icQw  = (const float*)d_in[16];
  const float* icQb  = (const float*)d_in[17];
  float* out = (float*)d_out;
  float* ws  = (float*)d_ws;

  // ---- workspace layout (float offsets) ----
  // he      @0          3,020,800  (-> Pbuf/qbuf/pbuf/s_pre after layer-1 LN)
  // s1      @3,020,800  3,020,800  (h1 -> Kbuf)
  // tmpb    @6,041,600  (bf16 [7552][416])
  // TB      @9,062,400  1,703,936  ([64][416][128] bf16)
  // gf/intraB @10,766,336 4,046,848 (gf fp32 [6400][400], then intraB bf16)
  // intra2B @14,813,184 4,046,848  (bf16 [19456][416])
  // wbase   @18,860,032   532,480  (1,064,960 ushorts) ; bias3 @19,392,512 (608)
  float* he    = ws;
  float* s1    = ws + 3020800;
  unsigned short* tmpb   = (unsigned short*)(ws + 6041600);
  unsigned short* TB     = (unsigned short*)(ws + 9062400);
  float* gf    = ws + 10766336;
  unsigned short* intraB = (unsigned short*)(ws + 10766336);
  unsigned short* intra2B= (unsigned short*)(ws + 14813184);
  unsigned short* wbase  = (unsigned short*)(ws + 18860032);
  float* bias3 = ws + 19392512;
  unsigned short* Pbuf = (unsigned short*)ws;
  float* qbuf  = ws + 1310720;                  // [1024][200]
  float* pbuf  = ws + 1515520;                  // [1024][400]
  float* s_pre = ws + 1925120;                  // [19456]
  float* Kbuf  = s1;
  unsigned short* gW0t  = wbase;
  unsigned short* gW1t  = wbase + 173056;
  unsigned short* afWt  = wbase + 346112;
  unsigned short* Kwt   = wbase + 519168;       // [224][416]
  unsigned short* icKwB = wbase + 612352;       // [416][224]
  unsigned short* icQwB = wbase + 705536;       // [416][224]
  unsigned short* Wqp   = wbase + 798720;       // [640][416]

  // 0. weight prep + fused icQ->p matrix
  k_prep_all<<<3513, 256, 0, stream>>>(gW, afW, Kw, Qw, icQw, icKw, Qbb, icQb, wbase, bias3);
  k_prep_M<<<13, 256, 0, stream>>>(icKwB, icQwB, Wqp);
  // 1. fused concat + transpose: he + hT
  k_toT_he<<<448, 256, 0, stream>>>(hist, proxy, he, TB);
  // 2-3. GCN layer 0 (LN epilogue also writes h1T -> TB)
  k_gmm<<<512, 256, 0, stream>>>(G, TB, tmpb);
  k_mgb_ln<0><<<BN / 16, 256, 0, stream>>>(tmpb, gW0t, gb, he, lns, lnb, s1, TB, nullptr);
  // 4-5. GCN layer 1 (LN epilogue computes gf = h2+he, writes gf fp32 + gfT -> TB)
  k_gmm<<<512, 256, 0, stream>>>(G, TB, tmpb);
  k_mgb_ln<1><<<BN / 16, 256, 0, stream>>>(tmpb, gW1t, gb + DD, s1, lns + DD, lnb + DD, gf, TB, he);
  // 6. K = gf @ Kw -> Kbuf (16-row tiles, grid 400 %8==0; overrun B reads in icKwB)
  k_mg16<400, 416, 200, 4, 0><<<BH / 16, 256, 0, stream>>>(gf, Kwt, nullptr, Kbuf, nullptr);
  // 7. fused Q-proj + p-proj (16-row tiles, grid 64 %8==0; Wqp padded to 640 rows)
  k_mg16<400, 416, 608, 10, 6><<<BB * NN / 16, 256, 0, stream>>>(cand, Wqp, bias3, qbuf, pbuf);
  // 8. alpha -> P (b-chunked XCD)
  k_palpha<<<BB * NN, 256, 0, stream>>>(Kbuf, qbuf, cidx, Pbuf);
  // 9. intra = P @ gf -> intraB bf16 (gf dead; same region, b-chunked XCD)
  k_sc<<<BB * CATN, 256, 0, stream>>>(Pbuf, TB, intraB);
  // 10. affine (16-row, grid 1216) + fused s-dot -> intra2B, s_pre
  k_afq<<<BB * NN * CATN / 16, 256, 0, stream>>>(intraB, afWt, afb, pbuf, s_pre, intra2B);
  // 11. final softmax + weighted sum (b-chunked XCD)
  k_final<<<BB * NN, 256, 0, stream>>>(intra2B, s_pre, cmask, out);
}